// Round 2
// baseline (6899.999 us; speedup 1.0000x reference)
//
#include <hip/hip_runtime.h>
#include <math.h>

#define B_   64
#define S_   512
#define E_   256
#define H_   256
#define G4H_ 1024
#define NT_  24

// ---- workspace layout (float-element offsets) ----
// hbuf2: [2 slot][2 dir][64 b][256 k] f32 = 65536 f   (zeroed once)
// flags: [2 slot][2 dir][4 bg][32 s] u32 = 512 f      (zeroed once)
// cstate: [2][B][H] = 32768 f
// whi/wlo: bf16 split of Wih_f/Wih_b, [2][1024][256] ushort = 262144 f each
// emisF/emisB: [B][S][NT]; hout_c then xpre_c (tc-sized)
static const size_t HBUF_OFF  = 0;
static const size_t FLG_OFF   = 65536;
static const size_t CST_OFF   = 131072;
static const size_t WHI_OFF   = 163840;
static const size_t WLO_OFF   = 425984;
static const size_t EMF_OFF   = 688128;
static const size_t EMB_OFF   = 1474560;
static const size_t HOUT_OFF  = 2260992;

typedef short  bf16x8_ __attribute__((ext_vector_type(8)));
typedef float  f32x4_  __attribute__((ext_vector_type(4)));

__device__ __forceinline__ float sigmoidf_(float x) {
  return 1.0f / (1.0f + expf(-x));
}

__device__ __forceinline__ unsigned short bf16_rne_(float v) {
  unsigned u = __float_as_uint(v);
  unsigned r = u + 0x7fffu + ((u >> 16) & 1u);
  return (unsigned short)(r >> 16);
}

// ============================================================================
// K0: split Wih_f/Wih_b into bf16 hi/lo planes (one-time, ~2 MB).
// grid = 512, block = 256; one float4 per thread.
// ============================================================================
__global__ __launch_bounds__(256) void k0_wconv(
    const float* __restrict__ Wf, const float* __restrict__ Wb,
    unsigned short* __restrict__ whi, unsigned short* __restrict__ wlo)
{
  int idx = blockIdx.x * 256 + threadIdx.x;  // f4 index over [2][65536]
  int d   = idx >> 16;
  int i4  = idx & 65535;
  const float* W = d ? Wb : Wf;
  float4 v = *(const float4*)(W + (size_t)i4 * 4);
  float vv[4] = {v.x, v.y, v.z, v.w};
  unsigned short h[4], l[4];
#pragma unroll
  for (int e = 0; e < 4; ++e) {
    h[e] = bf16_rne_(vv[e]);
    float hf = __uint_as_float((unsigned)h[e] << 16);
    l[e] = bf16_rne_(vv[e] - hf);
  }
  size_t o = (size_t)d * 262144 + (size_t)i4 * 4;
  whi[o + 0] = h[0]; whi[o + 1] = h[1]; whi[o + 2] = h[2]; whi[o + 3] = h[3];
  wlo[o + 0] = l[0]; wlo[o + 1] = l[1]; wlo[o + 2] = l[2]; wlo[o + 3] = l[3];
}

// ============================================================================
// K1: xpre via split-bf16 MFMA. xpre[m][n] = e[m] @ Wih^T[n] + bias[n],
// m = lt*64+b (tc*64 rows/dir), n = 1024, K = 256.
// Ozaki 2-split, all 4 cross products: err ~2^-18 rel (f32-comparable).
// WG tile 128x128, 4 waves of 64x64, K-slabs of 32 (8 slabs).
// grid = 8*tc, block = 256.
// ============================================================================
__global__ __launch_bounds__(256) void k1_xpre_mfma(
    const int* __restrict__ x, const float* __restrict__ emb,
    const unsigned short* __restrict__ whi,
    const unsigned short* __restrict__ wlo,
    const float* __restrict__ bih_f, const float* __restrict__ bhh_f,
    const float* __restrict__ bih_b, const float* __restrict__ bhh_b,
    float* __restrict__ xpre_c, int chunk, int tc)
{
  __shared__ unsigned short Ahi[128][40], Alo[128][40];  // stride 40: 16B-align
  __shared__ unsigned short Bhi[128][40], Blo[128][40];
  __shared__ int xt[128];

  const int tid = threadIdx.x;
  const int wg  = blockIdx.x;
  const int per_dir = 4 * tc;            // (tc/2) m-tiles * 8 n-tiles
  const int d   = wg / per_dir;
  const int rem = wg % per_dir;
  const int m0  = (rem >> 3) * 128;
  const int n0  = (rem & 7) * 128;
  const int t0  = chunk * tc;

  const float* bih = d ? bih_b : bih_f;
  const float* bhh = d ? bhh_b : bhh_f;
  const unsigned short* Whi = whi + (size_t)d * 262144;
  const unsigned short* Wlo = wlo + (size_t)d * 262144;

  if (tid < 128) {
    int m = m0 + tid;
    int lt = m >> 6, b = m & 63;
    int tok = d ? (S_ - 1 - (t0 + lt)) : (t0 + lt);
    xt[tid] = x[b * S_ + tok];
  }

  const int lane = tid & 63, wid = tid >> 6;
  const int wr = wid >> 1, wc = wid & 1;    // wave tile (64r x 64c)
  const int fr = lane & 15, fq = lane >> 4; // frag row/col and quad
  const int sr = tid >> 1, sh = tid & 1;    // staging row, k-half

  f32x4_ acc[4][4];
#pragma unroll
  for (int i = 0; i < 4; ++i)
#pragma unroll
    for (int j = 0; j < 4; ++j) acc[i][j] = (f32x4_){0.f, 0.f, 0.f, 0.f};

  for (int slab = 0; slab < 8; ++slab) {
    const int k0 = slab * 32;
    __syncthreads();   // covers xt[] on slab 0, prior frag reads after
    // stage A: emb row xt[sr], 16 cols, f32 -> bf16 hi/lo
    {
      const float* src = emb + (size_t)xt[sr] * E_ + k0 + sh * 16;
      unsigned short h[16], l[16];
#pragma unroll
      for (int q = 0; q < 4; ++q) {
        float4 v = *(const float4*)(src + q * 4);
        float vv[4] = {v.x, v.y, v.z, v.w};
#pragma unroll
        for (int e = 0; e < 4; ++e) {
          h[q * 4 + e] = bf16_rne_(vv[e]);
          float hf = __uint_as_float((unsigned)h[q * 4 + e] << 16);
          l[q * 4 + e] = bf16_rne_(vv[e] - hf);
        }
      }
      *(bf16x8_*)&Ahi[sr][sh * 16 + 0] = *(bf16x8_*)&h[0];
      *(bf16x8_*)&Ahi[sr][sh * 16 + 8] = *(bf16x8_*)&h[8];
      *(bf16x8_*)&Alo[sr][sh * 16 + 0] = *(bf16x8_*)&l[0];
      *(bf16x8_*)&Alo[sr][sh * 16 + 8] = *(bf16x8_*)&l[8];
    }
    // stage B: pre-split Wih rows (bf16 copy, no conversion)
    {
      const size_t o = (size_t)(n0 + sr) * E_ + k0 + sh * 16;
      *(bf16x8_*)&Bhi[sr][sh * 16 + 0] = *(const bf16x8_*)(Whi + o);
      *(bf16x8_*)&Bhi[sr][sh * 16 + 8] = *(const bf16x8_*)(Whi + o + 8);
      *(bf16x8_*)&Blo[sr][sh * 16 + 0] = *(const bf16x8_*)(Wlo + o);
      *(bf16x8_*)&Blo[sr][sh * 16 + 8] = *(const bf16x8_*)(Wlo + o + 8);
    }
    __syncthreads();

    bf16x8_ ah[4], al[4], bh[4], bl[4];
#pragma unroll
    for (int mi = 0; mi < 4; ++mi) {
      int row = 64 * wr + mi * 16 + fr;
      ah[mi] = *(bf16x8_*)&Ahi[row][fq * 8];
      al[mi] = *(bf16x8_*)&Alo[row][fq * 8];
    }
#pragma unroll
    for (int ni = 0; ni < 4; ++ni) {
      int row = 64 * wc + ni * 16 + fr;
      bh[ni] = *(bf16x8_*)&Bhi[row][fq * 8];
      bl[ni] = *(bf16x8_*)&Blo[row][fq * 8];
    }
#pragma unroll
    for (int mi = 0; mi < 4; ++mi)
#pragma unroll
      for (int ni = 0; ni < 4; ++ni) {
        acc[mi][ni] = __builtin_amdgcn_mfma_f32_16x16x32_bf16(
            al[mi], bl[ni], acc[mi][ni], 0, 0, 0);
        acc[mi][ni] = __builtin_amdgcn_mfma_f32_16x16x32_bf16(
            al[mi], bh[ni], acc[mi][ni], 0, 0, 0);
        acc[mi][ni] = __builtin_amdgcn_mfma_f32_16x16x32_bf16(
            ah[mi], bl[ni], acc[mi][ni], 0, 0, 0);
        acc[mi][ni] = __builtin_amdgcn_mfma_f32_16x16x32_bf16(
            ah[mi], bh[ni], acc[mi][ni], 0, 0, 0);
      }
  }

  // epilogue: D row = fq*4+reg (m), col = fr (n); add bias, store f32
  float bias[4];
#pragma unroll
  for (int ni = 0; ni < 4; ++ni) {
    int col = n0 + 64 * wc + ni * 16 + fr;
    bias[ni] = bih[col] + bhh[col];
  }
  const size_t base = (size_t)(d * tc * 64) * G4H_;
#pragma unroll
  for (int mi = 0; mi < 4; ++mi)
#pragma unroll
    for (int ni = 0; ni < 4; ++ni) {
      int col = n0 + 64 * wc + ni * 16 + fr;
#pragma unroll
      for (int r = 0; r < 4; ++r) {
        int m = m0 + 64 * wr + mi * 16 + fq * 4 + r;
        xpre_c[base + (size_t)m * G4H_ + col] = acc[mi][ni][r] + bias[ni];
      }
    }
}

// ============================================================================
// K2: biLSTM recurrence. Round-7: GEMM/pointwise restored to the EXACT round-5
// structure (970us best: 4b x 4r x 32k mapping, wreg[4][32], shfl_xor(32),
// single parity-buffered part[]). The h-exchange is rebuilt flag-based:
//   - producers store plain f32 h (agent-scope relaxed, [slot][d][b][k]),
//     then after __syncthreads (drains vmcnt) tid0 publishes ONE release
//     flag = t per WG.
//   - consumers poll 32 flags (one 4B load per producer WG, lanes 0..31 of
//     every wave) instead of 1024x8B tagged values -> ~32x less LLC poll
//     traffic, then load h ONCE as 8x u64 contiguous per lane.
// Rationale: round-5 counters show ~80% of the 9100cy/step is wait; the
// tag-poll scheme saturates the LLC with 4MB/round of redundant atomic loads,
// inflating the very visibility latency being waited on.
// Slot-reuse safety: producer reaches t+1 only after all peers published t,
// which is after they consumed t-1 (same induction as tag scheme).
// 256 WGs = dir(2) x batch-group(4 x 16b) x h-slice(32 x 8 rows), 1 WG/CU.
// ============================================================================
__global__ __launch_bounds__(256, 1) void k2_lstm(
    const float* __restrict__ Whh_f, const float* __restrict__ Whh_b,
    const float* __restrict__ xpre_c, float* __restrict__ hout_c,
    float* hbuf2, unsigned* flags, float* cstate, int chunk, int tc)
{
  __shared__ float hTb[16][260];         // [b_local][k + pad]
  __shared__ float part[2][4][16][36];   // [parity][wave][b][r]

  const int tid = threadIdx.x;
  const int wg  = blockIdx.x;
  const int d   = wg >> 7;
  const int bg  = (wg >> 5) & 3;
  const int s   = wg & 31;
  const int b0  = bg * 16;
  const float* Whh = d ? Whh_b : Whh_f;

  const int w     = tid >> 6;           // wave 0..3
  const int lane  = tid & 63;
  const int bl16  = lane & 15;          // staging batch
  const int kg    = w * 4 + (lane >> 4);  // k-group 0..15; k in [kg*16,kg*16+16)
  const int ks    = tid >> 5;           // GEMM k-chunk [32ks, 32ks+32)
  const int tl    = tid & 31, bt = tl & 3, rt = tl >> 2;
  const int pbl   = tid >> 3, pj = tid & 7;   // pointwise mapping (tid<128)

  // hoist this thread's Whh tile into registers (fixed for all steps)
  float wreg[4][32];
#pragma unroll
  for (int ri = 0; ri < 4; ++ri) {
    int r = rt * 4 + ri, g = r >> 3, j = r & 7;
    const float* src = Whh + ((size_t)(g * H_ + s * 8 + j)) * H_ + ks * 32;
#pragma unroll
    for (int q = 0; q < 8; ++q) {
      float4 v = *(const float4*)(src + q * 4);
      wreg[ri][q * 4 + 0] = v.x; wreg[ri][q * 4 + 1] = v.y;
      wreg[ri][q * 4 + 2] = v.z; wreg[ri][q * 4 + 3] = v.w;
    }
  }

  float c_reg = 0.0f;
  if (chunk > 0 && tid < 128)
    c_reg = cstate[((size_t)d * B_ + b0 + pbl) * H_ + s * 8 + pj];

  for (int tt = 1; tt <= tc; ++tt) {
    const int t  = chunk * tc + tt;   // global step 1..512
    const int lt = tt - 1;
    const int p  = tt & 1;

    // xpre prefetch (independent of h -> overlaps the flag poll)
    float xp[4];
    if (tid < 128) {
#pragma unroll
      for (int g = 0; g < 4; ++g)
        xp[g] = xpre_c[((size_t)(d * tc + lt) * B_ + b0 + pbl) * G4H_ +
                       g * H_ + s * 8 + pj];
    }

    // poll 32 producer flags (slot (t-1)&1); lanes 0..31 one flag each
    {
      const unsigned expt = (unsigned)(t - 1);
      const unsigned* fl =
          flags + (size_t)((((t - 1) & 1) * 2 + d) * 4 + bg) * 32;
      unsigned v = expt;
      if (lane < 32)
        v = __hip_atomic_load(fl + lane, __ATOMIC_RELAXED,
                              __HIP_MEMORY_SCOPE_AGENT);
      int lim = 0;
      while (__ballot(v != expt)) {
        if (++lim > (1 << 20)) break;   // deadlock safety
        if (v != expt)
          v = __hip_atomic_load(fl + lane, __ATOMIC_RELAXED,
                                __HIP_MEMORY_SCOPE_AGENT);
      }
    }

    // load h(t-1) once: 8 contiguous u64 per lane ([b][k] layout), stage LDS
    {
      const unsigned long long* hb = (const unsigned long long*)
          (hbuf2 + (size_t)(((t - 1) & 1) * 2 + d) * (64 * 256));
      const size_t a0 = ((size_t)(b0 + bl16) * 256 + kg * 16) >> 1;
      unsigned long long e[8];
#pragma unroll
      for (int i = 0; i < 8; ++i)
        e[i] = __hip_atomic_load(hb + a0 + i, __ATOMIC_RELAXED,
                                 __HIP_MEMORY_SCOPE_AGENT);
#pragma unroll
      for (int q = 0; q < 4; ++q) {
        float4 v;
        v.x = __uint_as_float((unsigned)e[2 * q]);
        v.y = __uint_as_float((unsigned)(e[2 * q] >> 32));
        v.z = __uint_as_float((unsigned)e[2 * q + 1]);
        v.w = __uint_as_float((unsigned)(e[2 * q + 1] >> 32));
        *(float4*)&hTb[bl16][kg * 16 + q * 4] = v;
      }
    }
    // no barrier: wave GEMM-reads only its own staged k-columns

    // GEMM: acc[bi][ri] += h[b][k] * W[k][r], weights from VGPRs
    float acc[4][4];
#pragma unroll
    for (int bi = 0; bi < 4; ++bi)
#pragma unroll
      for (int ri = 0; ri < 4; ++ri) acc[bi][ri] = 0.0f;
#pragma unroll
    for (int kq = 0; kq < 8; ++kq) {
      const int k0 = ks * 32 + kq * 4;
      float4 h4[4];
#pragma unroll
      for (int bi = 0; bi < 4; ++bi)
        h4[bi] = *(float4*)&hTb[bt * 4 + bi][k0];
#pragma unroll
      for (int kk = 0; kk < 4; ++kk) {
#pragma unroll
        for (int bi = 0; bi < 4; ++bi) {
          const float hv = kk == 0 ? h4[bi].x : kk == 1 ? h4[bi].y
                         : kk == 2 ? h4[bi].z : h4[bi].w;
#pragma unroll
          for (int ri = 0; ri < 4; ++ri)
            acc[bi][ri] = fmaf(hv, wreg[ri][kq * 4 + kk], acc[bi][ri]);
        }
      }
    }
    // reduce the two half-wave k-chunks, publish wave partial (b128)
#pragma unroll
    for (int bi = 0; bi < 4; ++bi)
#pragma unroll
      for (int ri = 0; ri < 4; ++ri)
        acc[bi][ri] += __shfl_xor(acc[bi][ri], 32, 64);
    if (lane < 32) {
#pragma unroll
      for (int bi = 0; bi < 4; ++bi) {
        float4 v = make_float4(acc[bi][0], acc[bi][1], acc[bi][2], acc[bi][3]);
        *(float4*)&part[p][w][bt * 4 + bi][rt * 4] = v;
      }
    }
    __syncthreads();   // B1: wave partials visible to pointwise waves

    if (tid < 128) {
      const int bglob = b0 + pbl;
      float gsum[4];
#pragma unroll
      for (int g = 0; g < 4; ++g) {
        const int r = g * 8 + pj;
        gsum[g] = xp[g] + ((part[p][0][pbl][r] + part[p][1][pbl][r]) +
                           (part[p][2][pbl][r] + part[p][3][pbl][r]));
      }
      float si = sigmoidf_(gsum[0]);
      float sf = sigmoidf_(gsum[1]);
      float tg = tanhf(gsum[2]);
      float so = sigmoidf_(gsum[3]);
      c_reg = sf * c_reg + si * tg;
      float h = so * tanhf(c_reg);
      __hip_atomic_store(hbuf2 + (size_t)((t & 1) * 2 + d) * (64 * 256) +
                             (size_t)bglob * 256 + s * 8 + pj,
                         h, __ATOMIC_RELAXED, __HIP_MEMORY_SCOPE_AGENT);
      hout_c[((size_t)(d * tc + lt) * B_ + bglob) * H_ + s * 8 + pj] = h;
    }
    __syncthreads();   // B2: drains h stores (vmcnt) before flag publish
    if (tid == 0)
      __hip_atomic_store(
          flags + (size_t)(((t & 1) * 2 + d) * 4 + bg) * 32 + s,
          (unsigned)t, __ATOMIC_RELEASE, __HIP_MEMORY_SCOPE_AGENT);
  }

  if (tid < 128)
    cstate[((size_t)d * B_ + b0 + pbl) * H_ + s * 8 + pj] = c_reg;
}

// ============================================================================
// K3: both directions' emission contributions in one launch.
// ============================================================================
__global__ __launch_bounds__(256) void k3_emis(
    const float* __restrict__ hout_c, const float* __restrict__ Wout,
    float* __restrict__ emisF, float* __restrict__ emisB, int chunk, int tc)
{
  __shared__ float hh[8][264];
  const int tid = threadIdx.x;
  const int nt8 = tc >> 3;
  const int per_d = 64 * nt8;
  const int d   = blockIdx.x / per_d;
  const int rem = blockIdx.x % per_d;
  const int b   = rem / nt8;
  const int lt0 = (rem % nt8) * 8;
  float* emisX = d ? emisB : emisF;
  {
    int r = tid >> 5, q = tid & 31;
    const float* src = hout_c + ((size_t)(d * tc + lt0 + r) * B_ + b) * H_;
#pragma unroll
    for (int i = 0; i < 2; ++i) {
      int f4i = q + 32 * i;
      *(float4*)&hh[r][f4i * 4] = *(const float4*)(src + f4i * 4);
    }
  }
  __syncthreads();
  if (tid < 192) {
    int r = tid / 24, tag = tid % 24;
    float acc = 0.0f;
    const float* w = Wout + (size_t)tag * 512 + d * 256;
#pragma unroll 4
    for (int k4 = 0; k4 < 64; ++k4) {
      float4 wv = *(const float4*)(w + k4 * 4);
      float4 hv = *(const float4*)&hh[r][k4 * 4];
      acc = fmaf(wv.x, hv.x, acc);
      acc = fmaf(wv.y, hv.y, acc);
      acc = fmaf(wv.z, hv.z, acc);
      acc = fmaf(wv.w, hv.w, acc);
    }
    int lt = lt0 + r;
    int tok = d ? (S_ - 1 - (chunk * tc + lt)) : (chunk * tc + lt);
    emisX[((size_t)b * S_ + tok) * NT_ + tag] = acc;
  }
}

// ============================================================================
// K4: Viterbi forward + backtrack; 1 wave per batch element.
// Preloads emisF+emisB (48KB), mask and transitions into LDS before the
// 511-step serial chain -> no global-memory latency on the chain.
// Summation order and first-max tie-break preserved exactly.
// ============================================================================
__global__ __launch_bounds__(64) void k4_viterbi(
    const float* __restrict__ emisF, const float* __restrict__ emisB,
    const float* __restrict__ bout, const unsigned char* __restrict__ mb,
    const float* __restrict__ trans, const float* __restrict__ startv,
    const float* __restrict__ endv, int* __restrict__ outp)
{
  __shared__ float tl[24 * 25];
  __shared__ __align__(16) float et[512][24];   // emisF+emisB per step, 48KB
  __shared__ unsigned char mk[512];
  __shared__ float sc[24];
  __shared__ float fin[24];
  __shared__ unsigned char hist[511 * 24];
  const int b = blockIdx.x;
  const int tid = threadIdx.x;
  const int is_bool = mb[1];

  for (int i = tid; i < 576; i += 64) tl[(i / 24) * 25 + (i % 24)] = trans[i];
  for (int t = tid; t < S_; t += 64) {
    int mi = b * S_ + t;
    mk[t] = is_bool ? mb[mi] : mb[mi << 2];
  }
  {
    const float4* eF = (const float4*)(emisF + (size_t)b * S_ * NT_);
    const float4* eB = (const float4*)(emisB + (size_t)b * S_ * NT_);
    float4* ed = (float4*)&et[0][0];
    for (int i = tid; i < (S_ * NT_) / 4; i += 64) {
      float4 a = eF[i], c = eB[i];
      ed[i] = make_float4(a.x + c.x, a.y + c.y, a.z + c.z, a.w + c.w);
    }
  }
  const float boutr = (tid < 24) ? bout[tid] : 0.0f;
  __syncthreads();

  if (tid < 24) sc[tid] = startv[tid] + (et[0][tid] + boutr);
  __syncthreads();

  for (int t = 1; t < S_; ++t) {
    float best = -3.4e38f, scj = 0.f;
    int idx = 0;
    const int m = mk[t];
    if (tid < 24) {
      float e = et[t][tid] + boutr;
      for (int i = 0; i < 24; ++i) {
        float v = (sc[i] + tl[i * 25 + tid]) + e;   // ref assoc order
        if (v > best) { best = v; idx = i; }
      }
      scj = sc[tid];
    }
    __syncthreads();
    if (tid < 24) {
      sc[tid] = m ? best : scj;
      hist[(t - 1) * 24 + tid] = (unsigned char)(m ? idx : tid);
    }
    __syncthreads();
  }
  if (tid < 24) fin[tid] = sc[tid] + endv[tid];
  __syncthreads();
  if (tid == 0) {
    int tag = 0; float best = fin[0];
    for (int i = 1; i < 24; ++i)
      if (fin[i] > best) { best = fin[i]; tag = i; }
    outp[b * S_ + (S_ - 1)] = tag;
    for (int tt = S_ - 2; tt >= 0; --tt) {
      tag = hist[tt * 24 + tag];
      outp[b * S_ + tt] = tag;
    }
  }
}

// ============================================================================
extern "C" void kernel_launch(void* const* d_in, const int* in_sizes, int n_in,
                              void* d_out, int out_size, void* d_ws,
                              size_t ws_size, hipStream_t stream)
{
  const int*   x      = (const int*)d_in[0];
  const unsigned char* maskb = (const unsigned char*)d_in[1];
  const float* emb    = (const float*)d_in[2];
  const float* Wih_f  = (const float*)d_in[3];
  const float* Whh_f  = (const float*)d_in[4];
  const float* bih_f  = (const float*)d_in[5];
  const float* bhh_f  = (const float*)d_in[6];
  const float* Wih_b  = (const float*)d_in[7];
  const float* Whh_b  = (const float*)d_in[8];
  const float* bih_b  = (const float*)d_in[9];
  const float* bhh_b  = (const float*)d_in[10];
  const float* Wout   = (const float*)d_in[11];
  const float* bout   = (const float*)d_in[12];
  const float* trans  = (const float*)d_in[13];
  const float* startv = (const float*)d_in[14];
  const float* endv   = (const float*)d_in[15];

  int tc = 8;
  {
    const int cand[6] = {512, 256, 128, 64, 32, 16};
    for (int i = 0; i < 6; ++i) {
      size_t needF = HOUT_OFF + (size_t)cand[i] * (2 * B_ * H_ + 2 * B_ * G4H_);
      if (needF * sizeof(float) <= ws_size) { tc = cand[i]; break; }
    }
  }
  const int nc = S_ / tc;

  float* ws     = (float*)d_ws;
  float* hbuf2  = ws + HBUF_OFF;
  unsigned* flags = (unsigned*)(ws + FLG_OFF);
  float* cstate = ws + CST_OFF;
  unsigned short* whi = (unsigned short*)(ws + WHI_OFF);
  unsigned short* wlo = (unsigned short*)(ws + WLO_OFF);
  float* emisF  = ws + EMF_OFF;
  float* emisB  = ws + EMB_OFF;
  float* hout_c = ws + HOUT_OFF;
  float* xpre_c = hout_c + (size_t)tc * 2 * B_ * H_;

  // zero hbuf2 + flags (h(0)=0, flags=0); ws is re-poisoned before launches
  hipMemsetAsync(d_ws, 0, 131072 * sizeof(float), stream);
  hipLaunchKernelGGL(k0_wconv, dim3(512), dim3(256), 0, stream,
                     Wih_f, Wih_b, whi, wlo);

  for (int c = 0; c < nc; ++c) {
    hipLaunchKernelGGL(k1_xpre_mfma, dim3(8 * tc), dim3(256), 0, stream,
                       x, emb, whi, wlo, bih_f, bhh_f, bih_b, bhh_b,
                       xpre_c, c, tc);
    hipLaunchKernelGGL(k2_lstm, dim3(256), dim3(256), 0, stream,
                       Whh_f, Whh_b, xpre_c, hout_c, hbuf2, flags, cstate,
                       c, tc);
    hipLaunchKernelGGL(k3_emis, dim3(2 * 64 * (tc / 8)), dim3(256), 0, stream,
                       hout_c, Wout, emisF, emisB, c, tc);
  }
  hipLaunchKernelGGL(k4_viterbi, dim3(64), dim3(64), 0, stream,
                     emisF, emisB, bout, maskb, trans, startv, endv,
                     (int*)d_out);
}

// Round 6
// 3799.232 us; speedup vs baseline: 1.8162x; 1.8162x over previous
//
#include <hip/hip_runtime.h>
#include <math.h>

#define B_   64
#define S_   512
#define E_   256
#define H_   256
#define G4H_ 1024
#define NT_  24

// ---- workspace layout (float-element offsets) ----
// hbuf : [2 slot][2 dir][64 b][256 k] f32, step-tag in mantissa LSB = 65536 f
//        init: slot0 = 0x00 bytes (tag 0 = h(0)), slot1 = 0x01 bytes (tag 1
//        = virtual h(-1)) — REQUIRED so t=2 cannot false-accept (round-5 bug)
// cstate: [2][B][H] = 32768 f
// whi/wlo: bf16 split of Wih_f/Wih_b, [2][1024][256] ushort = 262144 f each
// emisF/emisB: [B][S][NT]; hout_c then xpre_c (tc-sized)
static const size_t HBUF_OFF  = 0;
static const size_t CST_OFF   = 131072;
static const size_t WHI_OFF   = 163840;
static const size_t WLO_OFF   = 425984;
static const size_t EMF_OFF   = 689152;
static const size_t EMB_OFF   = 1475584;
static const size_t HOUT_OFF  = 2262016;

typedef short  bf16x8_ __attribute__((ext_vector_type(8)));
typedef float  f32x4_  __attribute__((ext_vector_type(4)));

__device__ __forceinline__ float sigmoidf_(float x) {
  return 1.0f / (1.0f + expf(-x));
}

__device__ __forceinline__ unsigned short bf16_rne_(float v) {
  unsigned u = __float_as_uint(v);
  unsigned r = u + 0x7fffu + ((u >> 16) & 1u);
  return (unsigned short)(r >> 16);
}

// ============================================================================
// K0: split Wih_f/Wih_b into bf16 hi/lo planes (one-time, ~2 MB).
// grid = 512, block = 256; one float4 per thread.
// ============================================================================
__global__ __launch_bounds__(256) void k0_wconv(
    const float* __restrict__ Wf, const float* __restrict__ Wb,
    unsigned short* __restrict__ whi, unsigned short* __restrict__ wlo)
{
  int idx = blockIdx.x * 256 + threadIdx.x;  // f4 index over [2][65536]
  int d   = idx >> 16;
  int i4  = idx & 65535;
  const float* W = d ? Wb : Wf;
  float4 v = *(const float4*)(W + (size_t)i4 * 4);
  float vv[4] = {v.x, v.y, v.z, v.w};
  unsigned short h[4], l[4];
#pragma unroll
  for (int e = 0; e < 4; ++e) {
    h[e] = bf16_rne_(vv[e]);
    float hf = __uint_as_float((unsigned)h[e] << 16);
    l[e] = bf16_rne_(vv[e] - hf);
  }
  size_t o = (size_t)d * 262144 + (size_t)i4 * 4;
  whi[o + 0] = h[0]; whi[o + 1] = h[1]; whi[o + 2] = h[2]; whi[o + 3] = h[3];
  wlo[o + 0] = l[0]; wlo[o + 1] = l[1]; wlo[o + 2] = l[2]; wlo[o + 3] = l[3];
}

// ============================================================================
// K1: xpre via split-bf16 MFMA. xpre[m][n] = e[m] @ Wih^T[n] + bias[n],
// m = lt*64+b (tc*64 rows/dir), n = 1024, K = 256.
// Ozaki 2-split, all 4 cross products: err ~2^-18 rel (f32-comparable).
// WG tile 128x128, 4 waves of 64x64, K-slabs of 32 (8 slabs).
// grid = 8*tc, block = 256.
// ============================================================================
__global__ __launch_bounds__(256) void k1_xpre_mfma(
    const int* __restrict__ x, const float* __restrict__ emb,
    const unsigned short* __restrict__ whi,
    const unsigned short* __restrict__ wlo,
    const float* __restrict__ bih_f, const float* __restrict__ bhh_f,
    const float* __restrict__ bih_b, const float* __restrict__ bhh_b,
    float* __restrict__ xpre_c, int chunk, int tc)
{
  __shared__ unsigned short Ahi[128][40], Alo[128][40];  // stride 40: 16B-align
  __shared__ unsigned short Bhi[128][40], Blo[128][40];
  __shared__ int xt[128];

  const int tid = threadIdx.x;
  const int wg  = blockIdx.x;
  const int per_dir = 4 * tc;            // (tc/2) m-tiles * 8 n-tiles
  const int d   = wg / per_dir;
  const int rem = wg % per_dir;
  const int m0  = (rem >> 3) * 128;
  const int n0  = (rem & 7) * 128;
  const int t0  = chunk * tc;

  const float* bih = d ? bih_b : bih_f;
  const float* bhh = d ? bhh_b : bhh_f;
  const unsigned short* Whi = whi + (size_t)d * 262144;
  const unsigned short* Wlo = wlo + (size_t)d * 262144;

  if (tid < 128) {
    int m = m0 + tid;
    int lt = m >> 6, b = m & 63;
    int tok = d ? (S_ - 1 - (t0 + lt)) : (t0 + lt);
    xt[tid] = x[b * S_ + tok];
  }

  const int lane = tid & 63, wid = tid >> 6;
  const int wr = wid >> 1, wc = wid & 1;    // wave tile (64r x 64c)
  const int fr = lane & 15, fq = lane >> 4; // frag row/col and quad
  const int sr = tid >> 1, sh = tid & 1;    // staging row, k-half

  f32x4_ acc[4][4];
#pragma unroll
  for (int i = 0; i < 4; ++i)
#pragma unroll
    for (int j = 0; j < 4; ++j) acc[i][j] = (f32x4_){0.f, 0.f, 0.f, 0.f};

  for (int slab = 0; slab < 8; ++slab) {
    const int k0 = slab * 32;
    __syncthreads();   // covers xt[] on slab 0, prior frag reads after
    // stage A: emb row xt[sr], 16 cols, f32 -> bf16 hi/lo
    {
      const float* src = emb + (size_t)xt[sr] * E_ + k0 + sh * 16;
      unsigned short h[16], l[16];
#pragma unroll
      for (int q = 0; q < 4; ++q) {
        float4 v = *(const float4*)(src + q * 4);
        float vv[4] = {v.x, v.y, v.z, v.w};
#pragma unroll
        for (int e = 0; e < 4; ++e) {
          h[q * 4 + e] = bf16_rne_(vv[e]);
          float hf = __uint_as_float((unsigned)h[q * 4 + e] << 16);
          l[q * 4 + e] = bf16_rne_(vv[e] - hf);
        }
      }
      *(bf16x8_*)&Ahi[sr][sh * 16 + 0] = *(bf16x8_*)&h[0];
      *(bf16x8_*)&Ahi[sr][sh * 16 + 8] = *(bf16x8_*)&h[8];
      *(bf16x8_*)&Alo[sr][sh * 16 + 0] = *(bf16x8_*)&l[0];
      *(bf16x8_*)&Alo[sr][sh * 16 + 8] = *(bf16x8_*)&l[8];
    }
    // stage B: pre-split Wih rows (bf16 copy, no conversion)
    {
      const size_t o = (size_t)(n0 + sr) * E_ + k0 + sh * 16;
      *(bf16x8_*)&Bhi[sr][sh * 16 + 0] = *(const bf16x8_*)(Whi + o);
      *(bf16x8_*)&Bhi[sr][sh * 16 + 8] = *(const bf16x8_*)(Whi + o + 8);
      *(bf16x8_*)&Blo[sr][sh * 16 + 0] = *(const bf16x8_*)(Wlo + o);
      *(bf16x8_*)&Blo[sr][sh * 16 + 8] = *(const bf16x8_*)(Wlo + o + 8);
    }
    __syncthreads();

    bf16x8_ ah[4], al[4], bh[4], bl[4];
#pragma unroll
    for (int mi = 0; mi < 4; ++mi) {
      int row = 64 * wr + mi * 16 + fr;
      ah[mi] = *(bf16x8_*)&Ahi[row][fq * 8];
      al[mi] = *(bf16x8_*)&Alo[row][fq * 8];
    }
#pragma unroll
    for (int ni = 0; ni < 4; ++ni) {
      int row = 64 * wc + ni * 16 + fr;
      bh[ni] = *(bf16x8_*)&Bhi[row][fq * 8];
      bl[ni] = *(bf16x8_*)&Blo[row][fq * 8];
    }
#pragma unroll
    for (int mi = 0; mi < 4; ++mi)
#pragma unroll
      for (int ni = 0; ni < 4; ++ni) {
        acc[mi][ni] = __builtin_amdgcn_mfma_f32_16x16x32_bf16(
            al[mi], bl[ni], acc[mi][ni], 0, 0, 0);
        acc[mi][ni] = __builtin_amdgcn_mfma_f32_16x16x32_bf16(
            al[mi], bh[ni], acc[mi][ni], 0, 0, 0);
        acc[mi][ni] = __builtin_amdgcn_mfma_f32_16x16x32_bf16(
            ah[mi], bl[ni], acc[mi][ni], 0, 0, 0);
        acc[mi][ni] = __builtin_amdgcn_mfma_f32_16x16x32_bf16(
            ah[mi], bh[ni], acc[mi][ni], 0, 0, 0);
      }
  }

  // epilogue: D row = fq*4+reg (m), col = fr (n); add bias, store f32
  float bias[4];
#pragma unroll
  for (int ni = 0; ni < 4; ++ni) {
    int col = n0 + 64 * wc + ni * 16 + fr;
    bias[ni] = bih[col] + bhh[col];
  }
  const size_t base = (size_t)(d * tc * 64) * G4H_;
#pragma unroll
  for (int mi = 0; mi < 4; ++mi)
#pragma unroll
    for (int ni = 0; ni < 4; ++ni) {
      int col = n0 + 64 * wc + ni * 16 + fr;
#pragma unroll
      for (int r = 0; r < 4; ++r) {
        int m = m0 + 64 * wr + mi * 16 + fq * 4 + r;
        xpre_c[base + (size_t)m * G4H_ + col] = acc[mi][ni][r] + bias[ni];
      }
    }
}

// ============================================================================
// K2: biLSTM recurrence — round-0 structure EXACTLY (tag-in-data streaming
// poll, agent scope via __hip_atomic_load/store only). Payload scheme:
//   hbuf entries are 4B f32 with the step tag in the mantissa LSB
//   (tagbit=(t>>1)&1; slot parity t&1 disambiguates). Slot occupants are
//   spaced 2 apart in t (skew bound by the consume-before-produce
//   induction: consumer at step t implies every producer completed t-2,
//   hence published h(t-3); occupant is h(t-3)/h(t-1)/h(t+1), adjacent
//   tags alternate). Same-address read-read coherence (guaranteed for
//   relaxed agent atomics) forbids regressing to an older occupant once
//   h(t-2) was observed at that location in step t-1. Boundary t=2 is
//   covered by INIT: slot1 bytes = 0x01 (tag 1 = virtual h(-1)) — round-5
//   zero-init falsely accepted h(1)=0 there.
//   Perturbation <= 2^-24 rel. Layout [slot][d][b][k]: each lane's 16
//   k-values are one contiguous 64B run -> 8x 8B agent atomic loads
//   (each 4B half self-validating). Poll bytes/round: 8MB -> 4MB chip-wide
//   (round-0 polls ran ~21 TB/s = LLC saturation; this halves pressure).
// 256 WGs = dir(2) x batch-group(4 x 16b) x h-slice(32 x 8 rows), 1 WG/CU.
// ============================================================================
__global__ __launch_bounds__(256, 1) void k2_lstm(
    const float* __restrict__ Whh_f, const float* __restrict__ Whh_b,
    const float* __restrict__ xpre_c, float* __restrict__ hout_c,
    unsigned* hbuf, float* cstate, int chunk, int tc)
{
  __shared__ float hTb[16][260];         // [b_local][k + pad]
  __shared__ float part[2][4][16][36];   // [parity][wave][b][r]

  const int tid = threadIdx.x;
  const int wg  = blockIdx.x;
  const int d   = wg >> 7;
  const int bg  = (wg >> 5) & 3;
  const int s   = wg & 31;
  const int b0  = bg * 16;
  const float* Whh = d ? Whh_b : Whh_f;

  const int w     = tid >> 6;           // wave 0..3
  const int lane  = tid & 63;
  const int bl16  = lane & 15;          // staging batch
  const int kb    = lane >> 4;          // 0..3
  const int kbase = w * 64 + kb * 16;   // staging k range [kbase, kbase+16)
  const int ks    = tid >> 5;           // GEMM k-chunk [32ks, 32ks+32)
  const int tl    = tid & 31, bt = tl & 3, rt = tl >> 2;
  const int pbl   = tid >> 3, pj = tid & 7;   // pointwise mapping (tid<128)

  // hoist this thread's Whh tile into registers (fixed for all steps)
  float wreg[4][32];
#pragma unroll
  for (int ri = 0; ri < 4; ++ri) {
    int r = rt * 4 + ri, g = r >> 3, j = r & 7;
    const float* src = Whh + ((size_t)(g * H_ + s * 8 + j)) * H_ + ks * 32;
#pragma unroll
    for (int q = 0; q < 8; ++q) {
      float4 v = *(const float4*)(src + q * 4);
      wreg[ri][q * 4 + 0] = v.x; wreg[ri][q * 4 + 1] = v.y;
      wreg[ri][q * 4 + 2] = v.z; wreg[ri][q * 4 + 3] = v.w;
    }
  }

  float c_reg = 0.0f;
  if (chunk > 0 && tid < 128)
    c_reg = cstate[((size_t)d * B_ + b0 + pbl) * H_ + s * 8 + pj];

  for (int tt = 1; tt <= tc; ++tt) {
    const int t  = chunk * tc + tt;   // global step 1..512
    const int lt = tt - 1;
    const int p  = tt & 1;

    // xpre prefetch (independent of h -> overlaps the poll)
    float xp[4];
    if (tid < 128) {
#pragma unroll
      for (int g = 0; g < 4; ++g)
        xp[g] = xpre_c[((size_t)(d * tc + lt) * B_ + b0 + pbl) * G4H_ +
                       g * H_ + s * 8 + pj];
    }

    // stage h(t-1): 8x 8B agent atomic loads (16 tagged f32, contiguous),
    // batched selective retry on stale tag bits — round-0 machinery.
    {
      const unsigned eb = ((unsigned)(t - 1) >> 1) & 1u;  // expected tag bit
      const unsigned long long ebp =
          (unsigned long long)eb * 0x0000000100000001ull;
      const unsigned long long* hb = (const unsigned long long*)
          (hbuf + (size_t)(((t - 1) & 1) * 2 + d) * (64 * 256) +
           (size_t)(b0 + bl16) * 256 + kbase);
      unsigned long long e[8];
#pragma unroll
      for (int i = 0; i < 8; ++i)
        e[i] = __hip_atomic_load(hb + i, __ATOMIC_RELAXED,
                                 __HIP_MEMORY_SCOPE_AGENT);
      int lim = 0;
      while (true) {
        unsigned bad = 0;
#pragma unroll
        for (int i = 0; i < 8; ++i)
          if ((e[i] ^ ebp) & 0x0000000100000001ull) bad |= (1u << i);
        if (bad == 0) break;
        if (++lim > (1 << 18)) break;   // deadlock safety
#pragma unroll
        for (int i = 0; i < 8; ++i)
          if (bad & (1u << i))
            e[i] = __hip_atomic_load(hb + i, __ATOMIC_RELAXED,
                                     __HIP_MEMORY_SCOPE_AGENT);
      }
      float4 v0, v1, v2, v3;
      v0.x = __uint_as_float((unsigned)e[0]);  v0.y = __uint_as_float((unsigned)(e[0] >> 32));
      v0.z = __uint_as_float((unsigned)e[1]);  v0.w = __uint_as_float((unsigned)(e[1] >> 32));
      v1.x = __uint_as_float((unsigned)e[2]);  v1.y = __uint_as_float((unsigned)(e[2] >> 32));
      v1.z = __uint_as_float((unsigned)e[3]);  v1.w = __uint_as_float((unsigned)(e[3] >> 32));
      v2.x = __uint_as_float((unsigned)e[4]);  v2.y = __uint_as_float((unsigned)(e[4] >> 32));
      v2.z = __uint_as_float((unsigned)e[5]);  v2.w = __uint_as_float((unsigned)(e[5] >> 32));
      v3.x = __uint_as_float((unsigned)e[6]);  v3.y = __uint_as_float((unsigned)(e[6] >> 32));
      v3.z = __uint_as_float((unsigned)e[7]);  v3.w = __uint_as_float((unsigned)(e[7] >> 32));
      *(float4*)&hTb[bl16][kbase +  0] = v0;
      *(float4*)&hTb[bl16][kbase +  4] = v1;
      *(float4*)&hTb[bl16][kbase +  8] = v2;
      *(float4*)&hTb[bl16][kbase + 12] = v3;
    }
    // no barrier: wave GEMM-reads only its own staged k-columns

    // GEMM: acc[bi][ri] += h[b][k] * W[k][r], weights from VGPRs
    float acc[4][4];
#pragma unroll
    for (int bi = 0; bi < 4; ++bi)
#pragma unroll
      for (int ri = 0; ri < 4; ++ri) acc[bi][ri] = 0.0f;
#pragma unroll
    for (int kq = 0; kq < 8; ++kq) {
      const int k0 = ks * 32 + kq * 4;
      float4 h4[4];
#pragma unroll
      for (int bi = 0; bi < 4; ++bi)
        h4[bi] = *(float4*)&hTb[bt * 4 + bi][k0];
#pragma unroll
      for (int kk = 0; kk < 4; ++kk) {
#pragma unroll
        for (int bi = 0; bi < 4; ++bi) {
          const float hv = kk == 0 ? h4[bi].x : kk == 1 ? h4[bi].y
                         : kk == 2 ? h4[bi].z : h4[bi].w;
#pragma unroll
          for (int ri = 0; ri < 4; ++ri)
            acc[bi][ri] = fmaf(hv, wreg[ri][kq * 4 + kk], acc[bi][ri]);
        }
      }
    }
    // reduce the two half-wave k-chunks, publish wave partial (b128)
#pragma unroll
    for (int bi = 0; bi < 4; ++bi)
#pragma unroll
      for (int ri = 0; ri < 4; ++ri)
        acc[bi][ri] += __shfl_xor(acc[bi][ri], 32, 64);
    if (lane < 32) {
#pragma unroll
      for (int bi = 0; bi < 4; ++bi) {
        float4 v = make_float4(acc[bi][0], acc[bi][1], acc[bi][2], acc[bi][3]);
        *(float4*)&part[p][w][bt * 4 + bi][rt * 4] = v;
      }
    }
    __syncthreads();   // B1: wave partials visible to pointwise waves

    if (tid < 128) {
      const int bglob = b0 + pbl;
      float gsum[4];
#pragma unroll
      for (int g = 0; g < 4; ++g) {
        const int r = g * 8 + pj;
        gsum[g] = xp[g] + ((part[p][0][pbl][r] + part[p][1][pbl][r]) +
                           (part[p][2][pbl][r] + part[p][3][pbl][r]));
      }
      float si = sigmoidf_(gsum[0]);
      float sf = sigmoidf_(gsum[1]);
      float tg = tanhf(gsum[2]);
      float so = sigmoidf_(gsum[3]);
      c_reg = sf * c_reg + si * tg;
      float h = so * tanhf(c_reg);
      // tag the mantissa LSB with (t>>1)&1; slot parity covers the rest
      unsigned hu = (__float_as_uint(h) & ~1u) | (((unsigned)t >> 1) & 1u);
      __hip_atomic_store(hbuf + (size_t)((t & 1) * 2 + d) * (64 * 256) +
                             (size_t)bglob * 256 + s * 8 + pj,
                         hu, __ATOMIC_RELAXED, __HIP_MEMORY_SCOPE_AGENT);
      hout_c[((size_t)(d * tc + lt) * B_ + bglob) * H_ + s * 8 + pj] = h;
    }
    // no B2: part is parity-double-buffered; B1 ordering protects reuse
  }

  if (tid < 128)
    cstate[((size_t)d * B_ + b0 + pbl) * H_ + s * 8 + pj] = c_reg;
}

// ============================================================================
// K3: both directions' emission contributions in one launch.
// ============================================================================
__global__ __launch_bounds__(256) void k3_emis(
    const float* __restrict__ hout_c, const float* __restrict__ Wout,
    float* __restrict__ emisF, float* __restrict__ emisB, int chunk, int tc)
{
  __shared__ float hh[8][264];
  const int tid = threadIdx.x;
  const int nt8 = tc >> 3;
  const int per_d = 64 * nt8;
  const int d   = blockIdx.x / per_d;
  const int rem = blockIdx.x % per_d;
  const int b   = rem / nt8;
  const int lt0 = (rem % nt8) * 8;
  float* emisX = d ? emisB : emisF;
  {
    int r = tid >> 5, q = tid & 31;
    const float* src = hout_c + ((size_t)(d * tc + lt0 + r) * B_ + b) * H_;
#pragma unroll
    for (int i = 0; i < 2; ++i) {
      int f4i = q + 32 * i;
      *(float4*)&hh[r][f4i * 4] = *(const float4*)(src + f4i * 4);
    }
  }
  __syncthreads();
  if (tid < 192) {
    int r = tid / 24, tag = tid % 24;
    float acc = 0.0f;
    const float* w = Wout + (size_t)tag * 512 + d * 256;
#pragma unroll 4
    for (int k4 = 0; k4 < 64; ++k4) {
      float4 wv = *(const float4*)(w + k4 * 4);
      float4 hv = *(const float4*)&hh[r][k4 * 4];
      acc = fmaf(wv.x, hv.x, acc);
      acc = fmaf(wv.y, hv.y, acc);
      acc = fmaf(wv.z, hv.z, acc);
      acc = fmaf(wv.w, hv.w, acc);
    }
    int lt = lt0 + r;
    int tok = d ? (S_ - 1 - (chunk * tc + lt)) : (chunk * tc + lt);
    emisX[((size_t)b * S_ + tok) * NT_ + tag] = acc;
  }
}

// ============================================================================
// K4: Viterbi forward + backtrack; 1 wave per batch element.
// Preloads emisF+emisB (48KB), mask and transitions into LDS before the
// 511-step serial chain -> no global-memory latency on the chain.
// Summation order and first-max tie-break preserved exactly. (Validated
// rounds 1-2, absmax 0.)
// ============================================================================
__global__ __launch_bounds__(64) void k4_viterbi(
    const float* __restrict__ emisF, const float* __restrict__ emisB,
    const float* __restrict__ bout, const unsigned char* __restrict__ mb,
    const float* __restrict__ trans, const float* __restrict__ startv,
    const float* __restrict__ endv, int* __restrict__ outp)
{
  __shared__ float tl[24 * 25];
  __shared__ __align__(16) float et[512][24];   // emisF+emisB per step, 48KB
  __shared__ unsigned char mk[512];
  __shared__ float sc[24];
  __shared__ float fin[24];
  __shared__ unsigned char hist[511 * 24];
  const int b = blockIdx.x;
  const int tid = threadIdx.x;
  const int is_bool = mb[1];

  for (int i = tid; i < 576; i += 64) tl[(i / 24) * 25 + (i % 24)] = trans[i];
  for (int t = tid; t < S_; t += 64) {
    int mi = b * S_ + t;
    mk[t] = is_bool ? mb[mi] : mb[mi << 2];
  }
  {
    const float4* eF = (const float4*)(emisF + (size_t)b * S_ * NT_);
    const float4* eB = (const float4*)(emisB + (size_t)b * S_ * NT_);
    float4* ed = (float4*)&et[0][0];
    for (int i = tid; i < (S_ * NT_) / 4; i += 64) {
      float4 a = eF[i], c = eB[i];
      ed[i] = make_float4(a.x + c.x, a.y + c.y, a.z + c.z, a.w + c.w);
    }
  }
  const float boutr = (tid < 24) ? bout[tid] : 0.0f;
  __syncthreads();

  if (tid < 24) sc[tid] = startv[tid] + (et[0][tid] + boutr);
  __syncthreads();

  for (int t = 1; t < S_; ++t) {
    float best = -3.4e38f, scj = 0.f;
    int idx = 0;
    const int m = mk[t];
    if (tid < 24) {
      float e = et[t][tid] + boutr;
      for (int i = 0; i < 24; ++i) {
        float v = (sc[i] + tl[i * 25 + tid]) + e;   // ref assoc order
        if (v > best) { best = v; idx = i; }
      }
      scj = sc[tid];
    }
    __syncthreads();
    if (tid < 24) {
      sc[tid] = m ? best : scj;
      hist[(t - 1) * 24 + tid] = (unsigned char)(m ? idx : tid);
    }
    __syncthreads();
  }
  if (tid < 24) fin[tid] = sc[tid] + endv[tid];
  __syncthreads();
  if (tid == 0) {
    int tag = 0; float best = fin[0];
    for (int i = 1; i < 24; ++i)
      if (fin[i] > best) { best = fin[i]; tag = i; }
    outp[b * S_ + (S_ - 1)] = tag;
    for (int tt = S_ - 2; tt >= 0; --tt) {
      tag = hist[tt * 24 + tag];
      outp[b * S_ + tt] = tag;
    }
  }
}

// ============================================================================
extern "C" void kernel_launch(void* const* d_in, const int* in_sizes, int n_in,
                              void* d_out, int out_size, void* d_ws,
                              size_t ws_size, hipStream_t stream)
{
  const int*   x      = (const int*)d_in[0];
  const unsigned char* maskb = (const unsigned char*)d_in[1];
  const float* emb    = (const float*)d_in[2];
  const float* Wih_f  = (const float*)d_in[3];
  const float* Whh_f  = (const float*)d_in[4];
  const float* bih_f  = (const float*)d_in[5];
  const float* bhh_f  = (const float*)d_in[6];
  const float* Wih_b  = (const float*)d_in[7];
  const float* Whh_b  = (const float*)d_in[8];
  const float* bih_b  = (const float*)d_in[9];
  const float* bhh_b  = (const float*)d_in[10];
  const float* Wout   = (const float*)d_in[11];
  const float* bout   = (const float*)d_in[12];
  const float* trans  = (const float*)d_in[13];
  const float* startv = (const float*)d_in[14];
  const float* endv   = (const float*)d_in[15];

  int tc = 8;
  {
    const int cand[6] = {512, 256, 128, 64, 32, 16};
    for (int i = 0; i < 6; ++i) {
      size_t needF = HOUT_OFF + (size_t)cand[i] * (2 * B_ * H_ + 2 * B_ * G4H_);
      if (needF * sizeof(float) <= ws_size) { tc = cand[i]; break; }
    }
  }
  const int nc = S_ / tc;

  float* ws     = (float*)d_ws;
  unsigned* hbuf = (unsigned*)(ws + HBUF_OFF);
  float* cstate = ws + CST_OFF;
  unsigned short* whi = (unsigned short*)(ws + WHI_OFF);
  unsigned short* wlo = (unsigned short*)(ws + WLO_OFF);
  float* emisF  = ws + EMF_OFF;
  float* emisB  = ws + EMB_OFF;
  float* hout_c = ws + HOUT_OFF;
  float* xpre_c = hout_c + (size_t)tc * 2 * B_ * H_;

  // init hbuf: slot0 = tag 0 (= real h(0)=0.0), slot1 = tag 1 (= virtual
  // h(-1), rejected by t=2's expected tag 0 until h(1) lands). Round-5 bug:
  // zeroing BOTH slots let t=2 false-accept slot1's initial zeros.
  hipMemsetAsync(hbuf, 0x00, 32768 * sizeof(float), stream);
  hipMemsetAsync(hbuf + 32768, 0x01, 32768 * sizeof(float), stream);
  hipLaunchKernelGGL(k0_wconv, dim3(512), dim3(256), 0, stream,
                     Wih_f, Wih_b, whi, wlo);

  for (int c = 0; c < nc; ++c) {
    hipLaunchKernelGGL(k1_xpre_mfma, dim3(8 * tc), dim3(256), 0, stream,
                       x, emb, whi, wlo, bih_f, bhh_f, bih_b, bhh_b,
                       xpre_c, c, tc);
    hipLaunchKernelGGL(k2_lstm, dim3(256), dim3(256), 0, stream,
                       Whh_f, Whh_b, xpre_c, hout_c, hbuf, cstate, c, tc);
    hipLaunchKernelGGL(k3_emis, dim3(2 * 64 * (tc / 8)), dim3(256), 0, stream,
                       hout_c, Wout, emisF, emisB, c, tc);
  }
  hipLaunchKernelGGL(k4_viterbi, dim3(64), dim3(64), 0, stream,
                     emisF, emisB, bout, maskb, trans, startv, endv,
                     (int*)d_out);
}

// Round 8
// 2981.814 us; speedup vs baseline: 2.3140x; 1.2741x over previous
//
#include <hip/hip_runtime.h>
#include <math.h>

#define B_   64
#define S_   512
#define E_   256
#define H_   256
#define G4H_ 1024
#define NT_  24

// ---- workspace layout (float-element offsets) ----
// hbuf : [2 slot][2 dir][256 k][64 b] f32, step-tag in mantissa LSB = 65536 f
//        init: slot0 = 0x00 bytes (tag 0 = h(0)), slot1 = 0x01 bytes (tag 1
//        = virtual h(-1)) — required so t=2 cannot false-accept (round-5 bug)
// cstate: [2][B][H] = 32768 f
// whi/wlo: bf16 split of Wih_f/Wih_b, [2][1024][256] ushort = 262144 f each
// emisF/emisB: [B][S][NT]; hout_c then xpre_c (tc-sized)
static const size_t HBUF_OFF  = 0;
static const size_t CST_OFF   = 131072;
static const size_t WHI_OFF   = 163840;
static const size_t WLO_OFF   = 425984;
static const size_t EMF_OFF   = 689152;
static const size_t EMB_OFF   = 1475584;
static const size_t HOUT_OFF  = 2262016;

typedef short  bf16x8_ __attribute__((ext_vector_type(8)));
typedef float  f32x4_  __attribute__((ext_vector_type(4)));

__device__ __forceinline__ float sigmoidf_(float x) {
  return 1.0f / (1.0f + expf(-x));
}

__device__ __forceinline__ unsigned short bf16_rne_(float v) {
  unsigned u = __float_as_uint(v);
  unsigned r = u + 0x7fffu + ((u >> 16) & 1u);
  return (unsigned short)(r >> 16);
}

// ============================================================================
// K0: split Wih_f/Wih_b into bf16 hi/lo planes (one-time, ~2 MB).
// grid = 512, block = 256; one float4 per thread.
// ============================================================================
__global__ __launch_bounds__(256) void k0_wconv(
    const float* __restrict__ Wf, const float* __restrict__ Wb,
    unsigned short* __restrict__ whi, unsigned short* __restrict__ wlo)
{
  int idx = blockIdx.x * 256 + threadIdx.x;  // f4 index over [2][65536]
  int d   = idx >> 16;
  int i4  = idx & 65535;
  const float* W = d ? Wb : Wf;
  float4 v = *(const float4*)(W + (size_t)i4 * 4);
  float vv[4] = {v.x, v.y, v.z, v.w};
  unsigned short h[4], l[4];
#pragma unroll
  for (int e = 0; e < 4; ++e) {
    h[e] = bf16_rne_(vv[e]);
    float hf = __uint_as_float((unsigned)h[e] << 16);
    l[e] = bf16_rne_(vv[e] - hf);
  }
  size_t o = (size_t)d * 262144 + (size_t)i4 * 4;
  whi[o + 0] = h[0]; whi[o + 1] = h[1]; whi[o + 2] = h[2]; whi[o + 3] = h[3];
  wlo[o + 0] = l[0]; wlo[o + 1] = l[1]; wlo[o + 2] = l[2]; wlo[o + 3] = l[3];
}

// ============================================================================
// K1: xpre via split-bf16 MFMA. xpre[m][n] = e[m] @ Wih^T[n] + bias[n],
// m = lt*64+b (tc*64 rows/dir), n = 1024, K = 256.
// Ozaki 2-split, all 4 cross products: err ~2^-18 rel (f32-comparable).
// WG tile 128x128, 4 waves of 64x64, K-slabs of 32 (8 slabs).
// grid = 8*tc, block = 256.
// ============================================================================
__global__ __launch_bounds__(256) void k1_xpre_mfma(
    const int* __restrict__ x, const float* __restrict__ emb,
    const unsigned short* __restrict__ whi,
    const unsigned short* __restrict__ wlo,
    const float* __restrict__ bih_f, const float* __restrict__ bhh_f,
    const float* __restrict__ bih_b, const float* __restrict__ bhh_b,
    float* __restrict__ xpre_c, int chunk, int tc)
{
  __shared__ unsigned short Ahi[128][40], Alo[128][40];  // stride 40: 16B-align
  __shared__ unsigned short Bhi[128][40], Blo[128][40];
  __shared__ int xt[128];

  const int tid = threadIdx.x;
  const int wg  = blockIdx.x;
  const int per_dir = 4 * tc;            // (tc/2) m-tiles * 8 n-tiles
  const int d   = wg / per_dir;
  const int rem = wg % per_dir;
  const int m0  = (rem >> 3) * 128;
  const int n0  = (rem & 7) * 128;
  const int t0  = chunk * tc;

  const float* bih = d ? bih_b : bih_f;
  const float* bhh = d ? bhh_b : bhh_f;
  const unsigned short* Whi = whi + (size_t)d * 262144;
  const unsigned short* Wlo = wlo + (size_t)d * 262144;

  if (tid < 128) {
    int m = m0 + tid;
    int lt = m >> 6, b = m & 63;
    int tok = d ? (S_ - 1 - (t0 + lt)) : (t0 + lt);
    xt[tid] = x[b * S_ + tok];
  }

  const int lane = tid & 63, wid = tid >> 6;
  const int wr = wid >> 1, wc = wid & 1;    // wave tile (64r x 64c)
  const int fr = lane & 15, fq = lane >> 4; // frag row/col and quad
  const int sr = tid >> 1, sh = tid & 1;    // staging row, k-half

  f32x4_ acc[4][4];
#pragma unroll
  for (int i = 0; i < 4; ++i)
#pragma unroll
    for (int j = 0; j < 4; ++j) acc[i][j] = (f32x4_){0.f, 0.f, 0.f, 0.f};

  for (int slab = 0; slab < 8; ++slab) {
    const int k0 = slab * 32;
    __syncthreads();   // covers xt[] on slab 0, prior frag reads after
    // stage A: emb row xt[sr], 16 cols, f32 -> bf16 hi/lo
    {
      const float* src = emb + (size_t)xt[sr] * E_ + k0 + sh * 16;
      unsigned short h[16], l[16];
#pragma unroll
      for (int q = 0; q < 4; ++q) {
        float4 v = *(const float4*)(src + q * 4);
        float vv[4] = {v.x, v.y, v.z, v.w};
#pragma unroll
        for (int e = 0; e < 4; ++e) {
          h[q * 4 + e] = bf16_rne_(vv[e]);
          float hf = __uint_as_float((unsigned)h[q * 4 + e] << 16);
          l[q * 4 + e] = bf16_rne_(vv[e] - hf);
        }
      }
      *(bf16x8_*)&Ahi[sr][sh * 16 + 0] = *(bf16x8_*)&h[0];
      *(bf16x8_*)&Ahi[sr][sh * 16 + 8] = *(bf16x8_*)&h[8];
      *(bf16x8_*)&Alo[sr][sh * 16 + 0] = *(bf16x8_*)&l[0];
      *(bf16x8_*)&Alo[sr][sh * 16 + 8] = *(bf16x8_*)&l[8];
    }
    // stage B: pre-split Wih rows (bf16 copy, no conversion)
    {
      const size_t o = (size_t)(n0 + sr) * E_ + k0 + sh * 16;
      *(bf16x8_*)&Bhi[sr][sh * 16 + 0] = *(const bf16x8_*)(Whi + o);
      *(bf16x8_*)&Bhi[sr][sh * 16 + 8] = *(const bf16x8_*)(Whi + o + 8);
      *(bf16x8_*)&Blo[sr][sh * 16 + 0] = *(const bf16x8_*)(Wlo + o);
      *(bf16x8_*)&Blo[sr][sh * 16 + 8] = *(const bf16x8_*)(Wlo + o + 8);
    }
    __syncthreads();

    bf16x8_ ah[4], al[4], bh[4], bl[4];
#pragma unroll
    for (int mi = 0; mi < 4; ++mi) {
      int row = 64 * wr + mi * 16 + fr;
      ah[mi] = *(bf16x8_*)&Ahi[row][fq * 8];
      al[mi] = *(bf16x8_*)&Alo[row][fq * 8];
    }
#pragma unroll
    for (int ni = 0; ni < 4; ++ni) {
      int row = 64 * wc + ni * 16 + fr;
      bh[ni] = *(bf16x8_*)&Bhi[row][fq * 8];
      bl[ni] = *(bf16x8_*)&Blo[row][fq * 8];
    }
#pragma unroll
    for (int mi = 0; mi < 4; ++mi)
#pragma unroll
      for (int ni = 0; ni < 4; ++ni) {
        acc[mi][ni] = __builtin_amdgcn_mfma_f32_16x16x32_bf16(
            al[mi], bl[ni], acc[mi][ni], 0, 0, 0);
        acc[mi][ni] = __builtin_amdgcn_mfma_f32_16x16x32_bf16(
            al[mi], bh[ni], acc[mi][ni], 0, 0, 0);
        acc[mi][ni] = __builtin_amdgcn_mfma_f32_16x16x32_bf16(
            ah[mi], bl[ni], acc[mi][ni], 0, 0, 0);
        acc[mi][ni] = __builtin_amdgcn_mfma_f32_16x16x32_bf16(
            ah[mi], bh[ni], acc[mi][ni], 0, 0, 0);
      }
  }

  // epilogue: D row = fq*4+reg (m), col = fr (n); add bias, store f32
  float bias[4];
#pragma unroll
  for (int ni = 0; ni < 4; ++ni) {
    int col = n0 + 64 * wc + ni * 16 + fr;
    bias[ni] = bih[col] + bhh[col];
  }
  const size_t base = (size_t)(d * tc * 64) * G4H_;
#pragma unroll
  for (int mi = 0; mi < 4; ++mi)
#pragma unroll
    for (int ni = 0; ni < 4; ++ni) {
      int col = n0 + 64 * wc + ni * 16 + fr;
#pragma unroll
      for (int r = 0; r < 4; ++r) {
        int m = m0 + 64 * wr + mi * 16 + fq * 4 + r;
        xpre_c[base + (size_t)m * G4H_ + col] = acc[mi][ni][r] + bias[ni];
      }
    }
}

// ============================================================================
// K2: biLSTM recurrence — round-0 structure with the validated 4B payload.
// Change vs round 6 (passed, but SLOWER): restore the [k][b] layout.
// Lesson from round-6 counters: poll cost is set by LLC line-REQUESTS per
// round, which depends on CROSS-LANE coalescing per instruction, not
// per-lane contiguity. [b][k] made every lane hit its own cache line
// (64 lines/instr); [k][b] makes lanes bl16=0..15 contiguous (4x 64B
// segments/instr). With 4B tagged entries: 64 line-requests per 4KB per
// wave-round = half the requests AND half the bytes of round 0.
//   Tag scheme (validated round 6): mantissa LSB = (t>>1)&1, slot parity
//   t&1; occupants spaced 2 in t, adjacent tags alternate; read-read
//   coherence forbids regression; slot1 init = 0x01 bytes covers t=2.
//   Perturbation <= 2^-24 rel.
// 256 WGs = dir(2) x batch-group(4 x 16b) x h-slice(32 x 8 rows), 1 WG/CU.
// ============================================================================
__global__ __launch_bounds__(256, 1) void k2_lstm(
    const float* __restrict__ Whh_f, const float* __restrict__ Whh_b,
    const float* __restrict__ xpre_c, float* __restrict__ hout_c,
    unsigned* hbuf, float* cstate, int chunk, int tc)
{
  __shared__ float hTb[16][260];         // [b_local][k + pad]
  __shared__ float part[2][4][16][36];   // [parity][wave][b][r]

  const int tid = threadIdx.x;
  const int wg  = blockIdx.x;
  const int d   = wg >> 7;
  const int bg  = (wg >> 5) & 3;
  const int s   = wg & 31;
  const int b0  = bg * 16;
  const float* Whh = d ? Whh_b : Whh_f;

  const int w     = tid >> 6;           // wave 0..3
  const int lane  = tid & 63;
  const int bl16  = lane & 15;          // staging batch
  const int kb    = lane >> 4;          // 0..3
  const int kbase = w * 64 + kb * 16;   // staging k range [kbase, kbase+16)
  const int ks    = tid >> 5;           // GEMM k-chunk [32ks, 32ks+32)
  const int tl    = tid & 31, bt = tl & 3, rt = tl >> 2;
  const int pbl   = tid >> 3, pj = tid & 7;   // pointwise mapping (tid<128)

  // hoist this thread's Whh tile into registers (fixed for all steps)
  float wreg[4][32];
#pragma unroll
  for (int ri = 0; ri < 4; ++ri) {
    int r = rt * 4 + ri, g = r >> 3, j = r & 7;
    const float* src = Whh + ((size_t)(g * H_ + s * 8 + j)) * H_ + ks * 32;
#pragma unroll
    for (int q = 0; q < 8; ++q) {
      float4 v = *(const float4*)(src + q * 4);
      wreg[ri][q * 4 + 0] = v.x; wreg[ri][q * 4 + 1] = v.y;
      wreg[ri][q * 4 + 2] = v.z; wreg[ri][q * 4 + 3] = v.w;
    }
  }

  float c_reg = 0.0f;
  if (chunk > 0 && tid < 128)
    c_reg = cstate[((size_t)d * B_ + b0 + pbl) * H_ + s * 8 + pj];

  for (int tt = 1; tt <= tc; ++tt) {
    const int t  = chunk * tc + tt;   // global step 1..512
    const int lt = tt - 1;
    const int p  = tt & 1;

    // xpre prefetch (independent of h -> overlaps the poll)
    float xp[4];
    if (tid < 128) {
#pragma unroll
      for (int g = 0; g < 4; ++g)
        xp[g] = xpre_c[((size_t)(d * tc + lt) * B_ + b0 + pbl) * G4H_ +
                       g * H_ + s * 8 + pj];
    }

    // stage h(t-1): 16 tagged 4B entries/lane at [k][b] (cross-lane
    // coalesced: lanes bl16=0..15 contiguous 64B), selective retry.
    {
      const unsigned eb = ((unsigned)(t - 1) >> 1) & 1u;  // expected tag bit
      const unsigned* hb = hbuf +
          (size_t)(((t - 1) & 1) * 2 + d) * (256 * 64) +
          (size_t)kbase * 64 + b0 + bl16;
      unsigned e[16];
#pragma unroll
      for (int i = 0; i < 16; ++i)
        e[i] = __hip_atomic_load(hb + (size_t)i * 64,
                                 __ATOMIC_RELAXED, __HIP_MEMORY_SCOPE_AGENT);
      int lim = 0;
      while (true) {
        unsigned bad = 0;
#pragma unroll
        for (int i = 0; i < 16; ++i)
          if ((e[i] ^ eb) & 1u) bad |= (1u << i);
        if (bad == 0) break;
        if (++lim > (1 << 18)) break;   // deadlock safety
#pragma unroll
        for (int i = 0; i < 16; ++i)
          if (bad & (1u << i))
            e[i] = __hip_atomic_load(hb + (size_t)i * 64,
                                     __ATOMIC_RELAXED,
                                     __HIP_MEMORY_SCOPE_AGENT);
      }
      float4 v0, v1, v2, v3;
      v0.x = __uint_as_float(e[0]);  v0.y = __uint_as_float(e[1]);
      v0.z = __uint_as_float(e[2]);  v0.w = __uint_as_float(e[3]);
      v1.x = __uint_as_float(e[4]);  v1.y = __uint_as_float(e[5]);
      v1.z = __uint_as_float(e[6]);  v1.w = __uint_as_float(e[7]);
      v2.x = __uint_as_float(e[8]);  v2.y = __uint_as_float(e[9]);
      v2.z = __uint_as_float(e[10]); v2.w = __uint_as_float(e[11]);
      v3.x = __uint_as_float(e[12]); v3.y = __uint_as_float(e[13]);
      v3.z = __uint_as_float(e[14]); v3.w = __uint_as_float(e[15]);
      *(float4*)&hTb[bl16][kbase +  0] = v0;
      *(float4*)&hTb[bl16][kbase +  4] = v1;
      *(float4*)&hTb[bl16][kbase +  8] = v2;
      *(float4*)&hTb[bl16][kbase + 12] = v3;
    }
    // no barrier: wave GEMM-reads only its own staged k-columns

    // GEMM: acc[bi][ri] += h[b][k] * W[k][r], weights from VGPRs
    float acc[4][4];
#pragma unroll
    for (int bi = 0; bi < 4; ++bi)
#pragma unroll
      for (int ri = 0; ri < 4; ++ri) acc[bi][ri] = 0.0f;
#pragma unroll
    for (int kq = 0; kq < 8; ++kq) {
      const int k0 = ks * 32 + kq * 4;
      float4 h4[4];
#pragma unroll
      for (int bi = 0; bi < 4; ++bi)
        h4[bi] = *(float4*)&hTb[bt * 4 + bi][k0];
#pragma unroll
      for (int kk = 0; kk < 4; ++kk) {
#pragma unroll
        for (int bi = 0; bi < 4; ++bi) {
          const float hv = kk == 0 ? h4[bi].x : kk == 1 ? h4[bi].y
                         : kk == 2 ? h4[bi].z : h4[bi].w;
#pragma unroll
          for (int ri = 0; ri < 4; ++ri)
            acc[bi][ri] = fmaf(hv, wreg[ri][kq * 4 + kk], acc[bi][ri]);
        }
      }
    }
    // reduce the two half-wave k-chunks, publish wave partial (b128)
#pragma unroll
    for (int bi = 0; bi < 4; ++bi)
#pragma unroll
      for (int ri = 0; ri < 4; ++ri)
        acc[bi][ri] += __shfl_xor(acc[bi][ri], 32, 64);
    if (lane < 32) {
#pragma unroll
      for (int bi = 0; bi < 4; ++bi) {
        float4 v = make_float4(acc[bi][0], acc[bi][1], acc[bi][2], acc[bi][3]);
        *(float4*)&part[p][w][bt * 4 + bi][rt * 4] = v;
      }
    }
    __syncthreads();   // B1: wave partials visible to pointwise waves

    if (tid < 128) {
      const int bglob = b0 + pbl;
      float gsum[4];
#pragma unroll
      for (int g = 0; g < 4; ++g) {
        const int r = g * 8 + pj;
        gsum[g] = xp[g] + ((part[p][0][pbl][r] + part[p][1][pbl][r]) +
                           (part[p][2][pbl][r] + part[p][3][pbl][r]));
      }
      float si = sigmoidf_(gsum[0]);
      float sf = sigmoidf_(gsum[1]);
      float tg = tanhf(gsum[2]);
      float so = sigmoidf_(gsum[3]);
      c_reg = sf * c_reg + si * tg;
      float h = so * tanhf(c_reg);
      // tag the mantissa LSB with (t>>1)&1; slot parity covers the rest
      unsigned hu = (__float_as_uint(h) & ~1u) | (((unsigned)t >> 1) & 1u);
      __hip_atomic_store(hbuf + (size_t)((t & 1) * 2 + d) * (256 * 64) +
                             (size_t)(s * 8 + pj) * 64 + bglob,
                         hu, __ATOMIC_RELAXED, __HIP_MEMORY_SCOPE_AGENT);
      hout_c[((size_t)(d * tc + lt) * B_ + bglob) * H_ + s * 8 + pj] = h;
    }
    // no B2: part is parity-double-buffered; B1 ordering protects reuse
  }

  if (tid < 128)
    cstate[((size_t)d * B_ + b0 + pbl) * H_ + s * 8 + pj] = c_reg;
}

// ============================================================================
// K3: both directions' emission contributions in one launch.
// ============================================================================
__global__ __launch_bounds__(256) void k3_emis(
    const float* __restrict__ hout_c, const float* __restrict__ Wout,
    float* __restrict__ emisF, float* __restrict__ emisB, int chunk, int tc)
{
  __shared__ float hh[8][264];
  const int tid = threadIdx.x;
  const int nt8 = tc >> 3;
  const int per_d = 64 * nt8;
  const int d   = blockIdx.x / per_d;
  const int rem = blockIdx.x % per_d;
  const int b   = rem / nt8;
  const int lt0 = (rem % nt8) * 8;
  float* emisX = d ? emisB : emisF;
  {
    int r = tid >> 5, q = tid & 31;
    const float* src = hout_c + ((size_t)(d * tc + lt0 + r) * B_ + b) * H_;
#pragma unroll
    for (int i = 0; i < 2; ++i) {
      int f4i = q + 32 * i;
      *(float4*)&hh[r][f4i * 4] = *(const float4*)(src + f4i * 4);
    }
  }
  __syncthreads();
  if (tid < 192) {
    int r = tid / 24, tag = tid % 24;
    float acc = 0.0f;
    const float* w = Wout + (size_t)tag * 512 + d * 256;
#pragma unroll 4
    for (int k4 = 0; k4 < 64; ++k4) {
      float4 wv = *(const float4*)(w + k4 * 4);
      float4 hv = *(const float4*)&hh[r][k4 * 4];
      acc = fmaf(wv.x, hv.x, acc);
      acc = fmaf(wv.y, hv.y, acc);
      acc = fmaf(wv.z, hv.z, acc);
      acc = fmaf(wv.w, hv.w, acc);
    }
    int lt = lt0 + r;
    int tok = d ? (S_ - 1 - (chunk * tc + lt)) : (chunk * tc + lt);
    emisX[((size_t)b * S_ + tok) * NT_ + tag] = acc;
  }
}

// ============================================================================
// K4: Viterbi forward + backtrack; 1 wave per batch element.
// Preloads emisF+emisB (48KB), mask and transitions into LDS before the
// 511-step serial chain -> no global-memory latency on the chain.
// Summation order and first-max tie-break preserved exactly. (Validated
// rounds 1-2 and 6, absmax 0.)
// ============================================================================
__global__ __launch_bounds__(64) void k4_viterbi(
    const float* __restrict__ emisF, const float* __restrict__ emisB,
    const float* __restrict__ bout, const unsigned char* __restrict__ mb,
    const float* __restrict__ trans, const float* __restrict__ startv,
    const float* __restrict__ endv, int* __restrict__ outp)
{
  __shared__ float tl[24 * 25];
  __shared__ __align__(16) float et[512][24];   // emisF+emisB per step, 48KB
  __shared__ unsigned char mk[512];
  __shared__ float sc[24];
  __shared__ float fin[24];
  __shared__ unsigned char hist[511 * 24];
  const int b = blockIdx.x;
  const int tid = threadIdx.x;
  const int is_bool = mb[1];

  for (int i = tid; i < 576; i += 64) tl[(i / 24) * 25 + (i % 24)] = trans[i];
  for (int t = tid; t < S_; t += 64) {
    int mi = b * S_ + t;
    mk[t] = is_bool ? mb[mi] : mb[mi << 2];
  }
  {
    const float4* eF = (const float4*)(emisF + (size_t)b * S_ * NT_);
    const float4* eB = (const float4*)(emisB + (size_t)b * S_ * NT_);
    float4* ed = (float4*)&et[0][0];
    for (int i = tid; i < (S_ * NT_) / 4; i += 64) {
      float4 a = eF[i], c = eB[i];
      ed[i] = make_float4(a.x + c.x, a.y + c.y, a.z + c.z, a.w + c.w);
    }
  }
  const float boutr = (tid < 24) ? bout[tid] : 0.0f;
  __syncthreads();

  if (tid < 24) sc[tid] = startv[tid] + (et[0][tid] + boutr);
  __syncthreads();

  for (int t = 1; t < S_; ++t) {
    float best = -3.4e38f, scj = 0.f;
    int idx = 0;
    const int m = mk[t];
    if (tid < 24) {
      float e = et[t][tid] + boutr;
      for (int i = 0; i < 24; ++i) {
        float v = (sc[i] + tl[i * 25 + tid]) + e;   // ref assoc order
        if (v > best) { best = v; idx = i; }
      }
      scj = sc[tid];
    }
    __syncthreads();
    if (tid < 24) {
      sc[tid] = m ? best : scj;
      hist[(t - 1) * 24 + tid] = (unsigned char)(m ? idx : tid);
    }
    __syncthreads();
  }
  if (tid < 24) fin[tid] = sc[tid] + endv[tid];
  __syncthreads();
  if (tid == 0) {
    int tag = 0; float best = fin[0];
    for (int i = 1; i < 24; ++i)
      if (fin[i] > best) { best = fin[i]; tag = i; }
    outp[b * S_ + (S_ - 1)] = tag;
    for (int tt = S_ - 2; tt >= 0; --tt) {
      tag = hist[tt * 24 + tag];
      outp[b * S_ + tt] = tag;
    }
  }
}

// ============================================================================
extern "C" void kernel_launch(void* const* d_in, const int* in_sizes, int n_in,
                              void* d_out, int out_size, void* d_ws,
                              size_t ws_size, hipStream_t stream)
{
  const int*   x      = (const int*)d_in[0];
  const unsigned char* maskb = (const unsigned char*)d_in[1];
  const float* emb    = (const float*)d_in[2];
  const float* Wih_f  = (const float*)d_in[3];
  const float* Whh_f  = (const float*)d_in[4];
  const float* bih_f  = (const float*)d_in[5];
  const float* bhh_f  = (const float*)d_in[6];
  const float* Wih_b  = (const float*)d_in[7];
  const float* Whh_b  = (const float*)d_in[8];
  const float* bih_b  = (const float*)d_in[9];
  const float* bhh_b  = (const float*)d_in[10];
  const float* Wout   = (const float*)d_in[11];
  const float* bout   = (const float*)d_in[12];
  const float* trans  = (const float*)d_in[13];
  const float* startv = (const float*)d_in[14];
  const float* endv   = (const float*)d_in[15];

  int tc = 8;
  {
    const int cand[6] = {512, 256, 128, 64, 32, 16};
    for (int i = 0; i < 6; ++i) {
      size_t needF = HOUT_OFF + (size_t)cand[i] * (2 * B_ * H_ + 2 * B_ * G4H_);
      if (needF * sizeof(float) <= ws_size) { tc = cand[i]; break; }
    }
  }
  const int nc = S_ / tc;

  float* ws     = (float*)d_ws;
  unsigned* hbuf = (unsigned*)(ws + HBUF_OFF);
  float* cstate = ws + CST_OFF;
  unsigned short* whi = (unsigned short*)(ws + WHI_OFF);
  unsigned short* wlo = (unsigned short*)(ws + WLO_OFF);
  float* emisF  = ws + EMF_OFF;
  float* emisB  = ws + EMB_OFF;
  float* hout_c = ws + HOUT_OFF;
  float* xpre_c = hout_c + (size_t)tc * 2 * B_ * H_;

  // init hbuf: slot0 = tag 0 (= real h(0)=0.0), slot1 = tag 1 (= virtual
  // h(-1), rejected by t=2's expected tag 0 until h(1) lands).
  hipMemsetAsync(hbuf, 0x00, 32768 * sizeof(float), stream);
  hipMemsetAsync(hbuf + 32768, 0x01, 32768 * sizeof(float), stream);
  hipLaunchKernelGGL(k0_wconv, dim3(512), dim3(256), 0, stream,
                     Wih_f, Wih_b, whi, wlo);

  for (int c = 0; c < nc; ++c) {
    hipLaunchKernelGGL(k1_xpre_mfma, dim3(8 * tc), dim3(256), 0, stream,
                       x, emb, whi, wlo, bih_f, bhh_f, bih_b, bhh_b,
                       xpre_c, c, tc);
    hipLaunchKernelGGL(k2_lstm, dim3(256), dim3(256), 0, stream,
                       Whh_f, Whh_b, xpre_c, hout_c, hbuf, cstate, c, tc);
    hipLaunchKernelGGL(k3_emis, dim3(2 * 64 * (tc / 8)), dim3(256), 0, stream,
                       hout_c, Wout, emisF, emisB, c, tc);
  }
  hipLaunchKernelGGL(k4_viterbi, dim3(64), dim3(64), 0, stream,
                     emisF, emisB, bout, maskb, trans, startv, endv,
                     (int*)d_out);
}

// Round 9
// 2630.512 us; speedup vs baseline: 2.6231x; 1.1335x over previous
//
#include <hip/hip_runtime.h>
#include <math.h>

#define B_   64
#define S_   512
#define E_   256
#define H_   256
#define G4H_ 1024
#define NT_  24

// ---- workspace layout (float-element offsets) ----
// hbuf : [2 slot][2 dir][256 k][64 b] x {float h, uint tag} = 131072 f (zeroed)
// cstate: [2][B][H] = 32768 f
// whi/wlo: bf16 split of Wih_f/Wih_b, [2][1024][256] ushort = 262144 f each
// emisF/emisB: [B][S][NT]; hout_c then xpre_c (tc-sized)
static const size_t HBUF_OFF  = 0;
static const size_t CST_OFF   = 131072;
static const size_t WHI_OFF   = 163840;
static const size_t WLO_OFF   = 425984;
static const size_t EMF_OFF   = 688128;
static const size_t EMB_OFF   = 1474560;
static const size_t HOUT_OFF  = 2260992;

typedef short  bf16x8_ __attribute__((ext_vector_type(8)));
typedef float  f32x4_  __attribute__((ext_vector_type(4)));

__device__ __forceinline__ float sigmoidf_(float x) {
  return 1.0f / (1.0f + expf(-x));
}

__device__ __forceinline__ unsigned short bf16_rne_(float v) {
  unsigned u = __float_as_uint(v);
  unsigned r = u + 0x7fffu + ((u >> 16) & 1u);
  return (unsigned short)(r >> 16);
}

// ============================================================================
// K0: split Wih_f/Wih_b into bf16 hi/lo planes (one-time, ~2 MB).
// grid = 512, block = 256; one float4 per thread.
// ============================================================================
__global__ __launch_bounds__(256) void k0_wconv(
    const float* __restrict__ Wf, const float* __restrict__ Wb,
    unsigned short* __restrict__ whi, unsigned short* __restrict__ wlo)
{
  int idx = blockIdx.x * 256 + threadIdx.x;  // f4 index over [2][65536]
  int d   = idx >> 16;
  int i4  = idx & 65535;
  const float* W = d ? Wb : Wf;
  float4 v = *(const float4*)(W + (size_t)i4 * 4);
  float vv[4] = {v.x, v.y, v.z, v.w};
  unsigned short h[4], l[4];
#pragma unroll
  for (int e = 0; e < 4; ++e) {
    h[e] = bf16_rne_(vv[e]);
    float hf = __uint_as_float((unsigned)h[e] << 16);
    l[e] = bf16_rne_(vv[e] - hf);
  }
  size_t o = (size_t)d * 262144 + (size_t)i4 * 4;
  whi[o + 0] = h[0]; whi[o + 1] = h[1]; whi[o + 2] = h[2]; whi[o + 3] = h[3];
  wlo[o + 0] = l[0]; wlo[o + 1] = l[1]; wlo[o + 2] = l[2]; wlo[o + 3] = l[3];
}

// ============================================================================
// K1: xpre via split-bf16 MFMA. xpre[m][n] = e[m] @ Wih^T[n] + bias[n],
// m = lt*64+b (tc*64 rows/dir), n = 1024, K = 256.
// Ozaki 2-split, all 4 cross products: err ~2^-18 rel (f32-comparable).
// WG tile 128x128, 4 waves of 64x64, K-slabs of 32 (8 slabs).
// grid = 8*tc, block = 256.
// ============================================================================
__global__ __launch_bounds__(256) void k1_xpre_mfma(
    const int* __restrict__ x, const float* __restrict__ emb,
    const unsigned short* __restrict__ whi,
    const unsigned short* __restrict__ wlo,
    const float* __restrict__ bih_f, const float* __restrict__ bhh_f,
    const float* __restrict__ bih_b, const float* __restrict__ bhh_b,
    float* __restrict__ xpre_c, int chunk, int tc)
{
  __shared__ unsigned short Ahi[128][40], Alo[128][40];  // stride 40: 16B-align
  __shared__ unsigned short Bhi[128][40], Blo[128][40];
  __shared__ int xt[128];

  const int tid = threadIdx.x;
  const int wg  = blockIdx.x;
  const int per_dir = 4 * tc;            // (tc/2) m-tiles * 8 n-tiles
  const int d   = wg / per_dir;
  const int rem = wg % per_dir;
  const int m0  = (rem >> 3) * 128;
  const int n0  = (rem & 7) * 128;
  const int t0  = chunk * tc;

  const float* bih = d ? bih_b : bih_f;
  const float* bhh = d ? bhh_b : bhh_f;
  const unsigned short* Whi = whi + (size_t)d * 262144;
  const unsigned short* Wlo = wlo + (size_t)d * 262144;

  if (tid < 128) {
    int m = m0 + tid;
    int lt = m >> 6, b = m & 63;
    int tok = d ? (S_ - 1 - (t0 + lt)) : (t0 + lt);
    xt[tid] = x[b * S_ + tok];
  }

  const int lane = tid & 63, wid = tid >> 6;
  const int wr = wid >> 1, wc = wid & 1;    // wave tile (64r x 64c)
  const int fr = lane & 15, fq = lane >> 4; // frag row/col and quad
  const int sr = tid >> 1, sh = tid & 1;    // staging row, k-half

  f32x4_ acc[4][4];
#pragma unroll
  for (int i = 0; i < 4; ++i)
#pragma unroll
    for (int j = 0; j < 4; ++j) acc[i][j] = (f32x4_){0.f, 0.f, 0.f, 0.f};

  for (int slab = 0; slab < 8; ++slab) {
    const int k0 = slab * 32;
    __syncthreads();   // covers xt[] on slab 0, prior frag reads after
    // stage A: emb row xt[sr], 16 cols, f32 -> bf16 hi/lo
    {
      const float* src = emb + (size_t)xt[sr] * E_ + k0 + sh * 16;
      unsigned short h[16], l[16];
#pragma unroll
      for (int q = 0; q < 4; ++q) {
        float4 v = *(const float4*)(src + q * 4);
        float vv[4] = {v.x, v.y, v.z, v.w};
#pragma unroll
        for (int e = 0; e < 4; ++e) {
          h[q * 4 + e] = bf16_rne_(vv[e]);
          float hf = __uint_as_float((unsigned)h[q * 4 + e] << 16);
          l[q * 4 + e] = bf16_rne_(vv[e] - hf);
        }
      }
      *(bf16x8_*)&Ahi[sr][sh * 16 + 0] = *(bf16x8_*)&h[0];
      *(bf16x8_*)&Ahi[sr][sh * 16 + 8] = *(bf16x8_*)&h[8];
      *(bf16x8_*)&Alo[sr][sh * 16 + 0] = *(bf16x8_*)&l[0];
      *(bf16x8_*)&Alo[sr][sh * 16 + 8] = *(bf16x8_*)&l[8];
    }
    // stage B: pre-split Wih rows (bf16 copy, no conversion)
    {
      const size_t o = (size_t)(n0 + sr) * E_ + k0 + sh * 16;
      *(bf16x8_*)&Bhi[sr][sh * 16 + 0] = *(const bf16x8_*)(Whi + o);
      *(bf16x8_*)&Bhi[sr][sh * 16 + 8] = *(const bf16x8_*)(Whi + o + 8);
      *(bf16x8_*)&Blo[sr][sh * 16 + 0] = *(const bf16x8_*)(Wlo + o);
      *(bf16x8_*)&Blo[sr][sh * 16 + 8] = *(const bf16x8_*)(Wlo + o + 8);
    }
    __syncthreads();

    bf16x8_ ah[4], al[4], bh[4], bl[4];
#pragma unroll
    for (int mi = 0; mi < 4; ++mi) {
      int row = 64 * wr + mi * 16 + fr;
      ah[mi] = *(bf16x8_*)&Ahi[row][fq * 8];
      al[mi] = *(bf16x8_*)&Alo[row][fq * 8];
    }
#pragma unroll
    for (int ni = 0; ni < 4; ++ni) {
      int row = 64 * wc + ni * 16 + fr;
      bh[ni] = *(bf16x8_*)&Bhi[row][fq * 8];
      bl[ni] = *(bf16x8_*)&Blo[row][fq * 8];
    }
#pragma unroll
    for (int mi = 0; mi < 4; ++mi)
#pragma unroll
      for (int ni = 0; ni < 4; ++ni) {
        acc[mi][ni] = __builtin_amdgcn_mfma_f32_16x16x32_bf16(
            al[mi], bl[ni], acc[mi][ni], 0, 0, 0);
        acc[mi][ni] = __builtin_amdgcn_mfma_f32_16x16x32_bf16(
            al[mi], bh[ni], acc[mi][ni], 0, 0, 0);
        acc[mi][ni] = __builtin_amdgcn_mfma_f32_16x16x32_bf16(
            ah[mi], bl[ni], acc[mi][ni], 0, 0, 0);
        acc[mi][ni] = __builtin_amdgcn_mfma_f32_16x16x32_bf16(
            ah[mi], bh[ni], acc[mi][ni], 0, 0, 0);
      }
  }

  // epilogue: D row = fq*4+reg (m), col = fr (n); add bias, store f32
  float bias[4];
#pragma unroll
  for (int ni = 0; ni < 4; ++ni) {
    int col = n0 + 64 * wc + ni * 16 + fr;
    bias[ni] = bih[col] + bhh[col];
  }
  const size_t base = (size_t)(d * tc * 64) * G4H_;
#pragma unroll
  for (int mi = 0; mi < 4; ++mi)
#pragma unroll
    for (int ni = 0; ni < 4; ++ni) {
      int col = n0 + 64 * wc + ni * 16 + fr;
#pragma unroll
      for (int r = 0; r < 4; ++r) {
        int m = m0 + 64 * wr + mi * 16 + fq * 4 + r;
        xpre_c[base + (size_t)m * G4H_ + col] = acc[mi][ni][r] + bias[ni];
      }
    }
}

// ============================================================================
// K2: biLSTM recurrence — EXACT round-0 structure (best measured: 970 us).
// Rounds 1-8 post-mortem: every exchange-path variation (flag-based, [b][k]
// layout, 4B tagged payloads) measured SLOWER (1113/3095/1570/1153) despite
// lower bytes/requests — the poll is convoy/latency-bound, not LLC-BW-bound.
// Reverted byte-for-byte: tag-in-data sync (full 32-bit step tag in the
// high word of an 8B {tag,h} pair), 128B-coalesced [k][b] staging, Whh in
// VGPRs, part[] parity-double-buffered, single __syncthreads per step.
// 256 WGs = dir(2) x batch-group(4 x 16b) x h-slice(32 x 8 rows), 1 WG/CU.
// ============================================================================
__global__ __launch_bounds__(256, 1) void k2_lstm(
    const float* __restrict__ Whh_f, const float* __restrict__ Whh_b,
    const float* __restrict__ xpre_c, float* __restrict__ hout_c,
    unsigned long long* hbuf, float* cstate, int chunk, int tc)
{
  __shared__ float hTb[16][260];         // [b_local][k + pad]
  __shared__ float part[2][4][16][36];   // [parity][wave][b][r]

  const int tid = threadIdx.x;
  const int wg  = blockIdx.x;
  const int d   = wg >> 7;
  const int bg  = (wg >> 5) & 3;
  const int s   = wg & 31;
  const int b0  = bg * 16;
  const float* Whh = d ? Whh_b : Whh_f;

  const int w     = tid >> 6;           // wave 0..3
  const int lane  = tid & 63;
  const int bl16  = lane & 15;          // staging batch
  const int kb    = lane >> 4;          // 0..3
  const int kbase = w * 64 + kb * 16;   // staging k range [kbase, kbase+16)
  const int ks    = tid >> 5;           // GEMM k-chunk [32ks, 32ks+32)
  const int tl    = tid & 31, bt = tl & 3, rt = tl >> 2;
  const int pbl   = tid >> 3, pj = tid & 7;   // pointwise mapping (tid<128)

  // hoist this thread's Whh tile into registers (fixed for all steps)
  float wreg[4][32];
#pragma unroll
  for (int ri = 0; ri < 4; ++ri) {
    int r = rt * 4 + ri, g = r >> 3, j = r & 7;
    const float* src = Whh + ((size_t)(g * H_ + s * 8 + j)) * H_ + ks * 32;
#pragma unroll
    for (int q = 0; q < 8; ++q) {
      float4 v = *(const float4*)(src + q * 4);
      wreg[ri][q * 4 + 0] = v.x; wreg[ri][q * 4 + 1] = v.y;
      wreg[ri][q * 4 + 2] = v.z; wreg[ri][q * 4 + 3] = v.w;
    }
  }

  float c_reg = 0.0f;
  if (chunk > 0 && tid < 128)
    c_reg = cstate[((size_t)d * B_ + b0 + pbl) * H_ + s * 8 + pj];

  for (int tt = 1; tt <= tc; ++tt) {
    const int t  = chunk * tc + tt;   // global step 1..512
    const int lt = tt - 1;
    const int p  = tt & 1;

    // xpre prefetch (independent of h -> overlaps the poll)
    float xp[4];
    if (tid < 128) {
#pragma unroll
      for (int g = 0; g < 4; ++g)
        xp[g] = xpre_c[((size_t)(d * tc + lt) * B_ + b0 + pbl) * G4H_ +
                       g * H_ + s * 8 + pj];
    }

    // stage h(t-1): 16 tagged entries/lane, batched retry on stale tags
    {
      const unsigned expt = (unsigned)(t - 1);
      const unsigned long long* hb =
          hbuf + ((size_t)(((t - 1) & 1) * 2 + d)) * (256 * 64);
      const size_t a0 = (size_t)kbase * 64 + b0 + bl16;
      unsigned long long e[16];
#pragma unroll
      for (int i = 0; i < 16; ++i)
        e[i] = __hip_atomic_load(hb + a0 + (size_t)i * 64,
                                 __ATOMIC_RELAXED, __HIP_MEMORY_SCOPE_AGENT);
      int lim = 0;
      while (true) {
        unsigned bad = 0;
#pragma unroll
        for (int i = 0; i < 16; ++i)
          if ((unsigned)(e[i] >> 32) != expt) bad |= (1u << i);
        if (bad == 0) break;
        if (++lim > (1 << 18)) break;   // deadlock safety
#pragma unroll
        for (int i = 0; i < 16; ++i)
          if (bad & (1u << i))
            e[i] = __hip_atomic_load(hb + a0 + (size_t)i * 64,
                                     __ATOMIC_RELAXED,
                                     __HIP_MEMORY_SCOPE_AGENT);
      }
      float4 v0, v1, v2, v3;
      v0.x = __uint_as_float((unsigned)e[0]);  v0.y = __uint_as_float((unsigned)e[1]);
      v0.z = __uint_as_float((unsigned)e[2]);  v0.w = __uint_as_float((unsigned)e[3]);
      v1.x = __uint_as_float((unsigned)e[4]);  v1.y = __uint_as_float((unsigned)e[5]);
      v1.z = __uint_as_float((unsigned)e[6]);  v1.w = __uint_as_float((unsigned)e[7]);
      v2.x = __uint_as_float((unsigned)e[8]);  v2.y = __uint_as_float((unsigned)e[9]);
      v2.z = __uint_as_float((unsigned)e[10]); v2.w = __uint_as_float((unsigned)e[11]);
      v3.x = __uint_as_float((unsigned)e[12]); v3.y = __uint_as_float((unsigned)e[13]);
      v3.z = __uint_as_float((unsigned)e[14]); v3.w = __uint_as_float((unsigned)e[15]);
      *(float4*)&hTb[bl16][kbase +  0] = v0;
      *(float4*)&hTb[bl16][kbase +  4] = v1;
      *(float4*)&hTb[bl16][kbase +  8] = v2;
      *(float4*)&hTb[bl16][kbase + 12] = v3;
    }
    // no barrier: wave GEMM-reads only its own staged k-columns

    // GEMM: acc[bi][ri] += h[b][k] * W[k][r], weights from VGPRs
    float acc[4][4];
#pragma unroll
    for (int bi = 0; bi < 4; ++bi)
#pragma unroll
      for (int ri = 0; ri < 4; ++ri) acc[bi][ri] = 0.0f;
#pragma unroll
    for (int kq = 0; kq < 8; ++kq) {
      const int k0 = ks * 32 + kq * 4;
      float4 h4[4];
#pragma unroll
      for (int bi = 0; bi < 4; ++bi)
        h4[bi] = *(float4*)&hTb[bt * 4 + bi][k0];
#pragma unroll
      for (int kk = 0; kk < 4; ++kk) {
#pragma unroll
        for (int bi = 0; bi < 4; ++bi) {
          const float hv = kk == 0 ? h4[bi].x : kk == 1 ? h4[bi].y
                         : kk == 2 ? h4[bi].z : h4[bi].w;
#pragma unroll
          for (int ri = 0; ri < 4; ++ri)
            acc[bi][ri] = fmaf(hv, wreg[ri][kq * 4 + kk], acc[bi][ri]);
        }
      }
    }
    // reduce the two half-wave k-chunks, publish wave partial (b128)
#pragma unroll
    for (int bi = 0; bi < 4; ++bi)
#pragma unroll
      for (int ri = 0; ri < 4; ++ri)
        acc[bi][ri] += __shfl_xor(acc[bi][ri], 32, 64);
    if (lane < 32) {
#pragma unroll
      for (int bi = 0; bi < 4; ++bi) {
        float4 v = make_float4(acc[bi][0], acc[bi][1], acc[bi][2], acc[bi][3]);
        *(float4*)&part[p][w][bt * 4 + bi][rt * 4] = v;
      }
    }
    __syncthreads();   // B1: wave partials visible to pointwise waves

    if (tid < 128) {
      const int bglob = b0 + pbl;
      float gsum[4];
#pragma unroll
      for (int g = 0; g < 4; ++g) {
        const int r = g * 8 + pj;
        gsum[g] = xp[g] + ((part[p][0][pbl][r] + part[p][1][pbl][r]) +
                           (part[p][2][pbl][r] + part[p][3][pbl][r]));
      }
      float si = sigmoidf_(gsum[0]);
      float sf = sigmoidf_(gsum[1]);
      float tg = tanhf(gsum[2]);
      float so = sigmoidf_(gsum[3]);
      c_reg = sf * c_reg + si * tg;
      float h = so * tanhf(c_reg);
      unsigned long long pk =
          (((unsigned long long)(unsigned)t) << 32) |
          (unsigned long long)__float_as_uint(h);
      __hip_atomic_store(hbuf + ((size_t)((t & 1) * 2 + d)) * (256 * 64) +
                             (size_t)(s * 8 + pj) * 64 + bglob,
                         pk, __ATOMIC_RELAXED, __HIP_MEMORY_SCOPE_AGENT);
      hout_c[((size_t)(d * tc + lt) * B_ + bglob) * H_ + s * 8 + pj] = h;
    }
    // no B2: part is parity-double-buffered; B1 ordering protects reuse
  }

  if (tid < 128)
    cstate[((size_t)d * B_ + b0 + pbl) * H_ + s * 8 + pj] = c_reg;
}

// ============================================================================
// K3: both directions' emission contributions in one launch.
// ============================================================================
__global__ __launch_bounds__(256) void k3_emis(
    const float* __restrict__ hout_c, const float* __restrict__ Wout,
    float* __restrict__ emisF, float* __restrict__ emisB, int chunk, int tc)
{
  __shared__ float hh[8][264];
  const int tid = threadIdx.x;
  const int nt8 = tc >> 3;
  const int per_d = 64 * nt8;
  const int d   = blockIdx.x / per_d;
  const int rem = blockIdx.x % per_d;
  const int b   = rem / nt8;
  const int lt0 = (rem % nt8) * 8;
  float* emisX = d ? emisB : emisF;
  {
    int r = tid >> 5, q = tid & 31;
    const float* src = hout_c + ((size_t)(d * tc + lt0 + r) * B_ + b) * H_;
#pragma unroll
    for (int i = 0; i < 2; ++i) {
      int f4i = q + 32 * i;
      *(float4*)&hh[r][f4i * 4] = *(const float4*)(src + f4i * 4);
    }
  }
  __syncthreads();
  if (tid < 192) {
    int r = tid / 24, tag = tid % 24;
    float acc = 0.0f;
    const float* w = Wout + (size_t)tag * 512 + d * 256;
#pragma unroll 4
    for (int k4 = 0; k4 < 64; ++k4) {
      float4 wv = *(const float4*)(w + k4 * 4);
      float4 hv = *(const float4*)&hh[r][k4 * 4];
      acc = fmaf(wv.x, hv.x, acc);
      acc = fmaf(wv.y, hv.y, acc);
      acc = fmaf(wv.z, hv.z, acc);
      acc = fmaf(wv.w, hv.w, acc);
    }
    int lt = lt0 + r;
    int tok = d ? (S_ - 1 - (chunk * tc + lt)) : (chunk * tc + lt);
    emisX[((size_t)b * S_ + tok) * NT_ + tag] = acc;
  }
}

// ============================================================================
// K4: Viterbi forward + backtrack; 1 wave per batch element.
// Preloads emisF+emisB (48KB), mask and transitions into LDS before the
// 511-step serial chain -> no global-memory latency on the chain.
// Summation order and first-max tie-break preserved exactly. (Validated
// rounds 1-2, 6, 8 — absmax 0.)
// ============================================================================
__global__ __launch_bounds__(64) void k4_viterbi(
    const float* __restrict__ emisF, const float* __restrict__ emisB,
    const float* __restrict__ bout, const unsigned char* __restrict__ mb,
    const float* __restrict__ trans, const float* __restrict__ startv,
    const float* __restrict__ endv, int* __restrict__ outp)
{
  __shared__ float tl[24 * 25];
  __shared__ __align__(16) float et[512][24];   // emisF+emisB per step, 48KB
  __shared__ unsigned char mk[512];
  __shared__ float sc[24];
  __shared__ float fin[24];
  __shared__ unsigned char hist[511 * 24];
  const int b = blockIdx.x;
  const int tid = threadIdx.x;
  const int is_bool = mb[1];

  for (int i = tid; i < 576; i += 64) tl[(i / 24) * 25 + (i % 24)] = trans[i];
  for (int t = tid; t < S_; t += 64) {
    int mi = b * S_ + t;
    mk[t] = is_bool ? mb[mi] : mb[mi << 2];
  }
  {
    const float4* eF = (const float4*)(emisF + (size_t)b * S_ * NT_);
    const float4* eB = (const float4*)(emisB + (size_t)b * S_ * NT_);
    float4* ed = (float4*)&et[0][0];
    for (int i = tid; i < (S_ * NT_) / 4; i += 64) {
      float4 a = eF[i], c = eB[i];
      ed[i] = make_float4(a.x + c.x, a.y + c.y, a.z + c.z, a.w + c.w);
    }
  }
  const float boutr = (tid < 24) ? bout[tid] : 0.0f;
  __syncthreads();

  if (tid < 24) sc[tid] = startv[tid] + (et[0][tid] + boutr);
  __syncthreads();

  for (int t = 1; t < S_; ++t) {
    float best = -3.4e38f, scj = 0.f;
    int idx = 0;
    const int m = mk[t];
    if (tid < 24) {
      float e = et[t][tid] + boutr;
      for (int i = 0; i < 24; ++i) {
        float v = (sc[i] + tl[i * 25 + tid]) + e;   // ref assoc order
        if (v > best) { best = v; idx = i; }
      }
      scj = sc[tid];
    }
    __syncthreads();
    if (tid < 24) {
      sc[tid] = m ? best : scj;
      hist[(t - 1) * 24 + tid] = (unsigned char)(m ? idx : tid);
    }
    __syncthreads();
  }
  if (tid < 24) fin[tid] = sc[tid] + endv[tid];
  __syncthreads();
  if (tid == 0) {
    int tag = 0; float best = fin[0];
    for (int i = 1; i < 24; ++i)
      if (fin[i] > best) { best = fin[i]; tag = i; }
    outp[b * S_ + (S_ - 1)] = tag;
    for (int tt = S_ - 2; tt >= 0; --tt) {
      tag = hist[tt * 24 + tag];
      outp[b * S_ + tt] = tag;
    }
  }
}

// ============================================================================
extern "C" void kernel_launch(void* const* d_in, const int* in_sizes, int n_in,
                              void* d_out, int out_size, void* d_ws,
                              size_t ws_size, hipStream_t stream)
{
  const int*   x      = (const int*)d_in[0];
  const unsigned char* maskb = (const unsigned char*)d_in[1];
  const float* emb    = (const float*)d_in[2];
  const float* Wih_f  = (const float*)d_in[3];
  const float* Whh_f  = (const float*)d_in[4];
  const float* bih_f  = (const float*)d_in[5];
  const float* bhh_f  = (const float*)d_in[6];
  const float* Wih_b  = (const float*)d_in[7];
  const float* Whh_b  = (const float*)d_in[8];
  const float* bih_b  = (const float*)d_in[9];
  const float* bhh_b  = (const float*)d_in[10];
  const float* Wout   = (const float*)d_in[11];
  const float* bout   = (const float*)d_in[12];
  const float* trans  = (const float*)d_in[13];
  const float* startv = (const float*)d_in[14];
  const float* endv   = (const float*)d_in[15];

  int tc = 8;
  {
    const int cand[6] = {512, 256, 128, 64, 32, 16};
    for (int i = 0; i < 6; ++i) {
      size_t needF = HOUT_OFF + (size_t)cand[i] * (2 * B_ * H_ + 2 * B_ * G4H_);
      if (needF * sizeof(float) <= ws_size) { tc = cand[i]; break; }
    }
  }
  const int nc = S_ / tc;

  float* ws     = (float*)d_ws;
  unsigned long long* hbuf = (unsigned long long*)(ws + HBUF_OFF);
  float* cstate = ws + CST_OFF;
  unsigned short* whi = (unsigned short*)(ws + WHI_OFF);
  unsigned short* wlo = (unsigned short*)(ws + WLO_OFF);
  float* emisF  = ws + EMF_OFF;
  float* emisB  = ws + EMB_OFF;
  float* hout_c = ws + HOUT_OFF;
  float* xpre_c = hout_c + (size_t)tc * 2 * B_ * H_;

  // zero hbuf (h(0)=0, tags=0); ws is re-poisoned 0xAA before every launch
  hipMemsetAsync(d_ws, 0, 131072 * sizeof(float), stream);
  hipLaunchKernelGGL(k0_wconv, dim3(512), dim3(256), 0, stream,
                     Wih_f, Wih_b, whi, wlo);

  for (int c = 0; c < nc; ++c) {
    hipLaunchKernelGGL(k1_xpre_mfma, dim3(8 * tc), dim3(256), 0, stream,
                       x, emb, whi, wlo, bih_f, bhh_f, bih_b, bhh_b,
                       xpre_c, c, tc);
    hipLaunchKernelGGL(k2_lstm, dim3(256), dim3(256), 0, stream,
                       Whh_f, Whh_b, xpre_c, hout_c, hbuf, cstate, c, tc);
    hipLaunchKernelGGL(k3_emis, dim3(2 * 64 * (tc / 8)), dim3(256), 0, stream,
                       hout_c, Wout, emisF, emisB, c, tc);
  }
  hipLaunchKernelGGL(k4_viterbi, dim3(64), dim3(64), 0, stream,
                     emisF, emisB, bout, maskb, trans, startv, endv,
                     (int*)d_out);
}